// Round 16
// baseline (3184.262 us; speedup 1.0000x reference)
//
#include <hip/hip_runtime.h>
#include <math.h>

#define NTHR 1024

constexpr int EG_STRIDE = 16384;   // floats per batch: e1 only (128 rows x 128)

__device__ __forceinline__ int xoff(int l) { return 512 - (512 >> l); }   // l in 0..7

// ---- MLP chunk, C rows (l0, l4, uniform-descent C1): R3 register shape +
// DEPTH-1 prefetch (R10: depth-2 -> 330 MB spill; depth-1 is the ceiling).
// `#pragma unroll 1` on k-loops is load-bearing (R1/R2 spill lesson).
template <int C>
__device__ __forceinline__ void mlp_chunk(
    const float* zl, int zstr,
    const float* __restrict__ W1, const float* __restrict__ B1,
    const float* __restrict__ W2, const float* __restrict__ B2,
    const float* lab, bool uselab, const short* u1h, int done,
    float* red, float* h, float* eout)
{
  const int t  = threadIdx.x;
  const int wv = t >> 6;
  const int ln = t & 63;
  // ---------- layer 1 ----------
  {
    const int kg = wv >> 1;
    const int c1 = (wv & 1) * 128 + 2 * ln;
    const float* wb = W1 + 32 * kg * 256 + c1;
    const float* zb = zl + 32 * kg;
    float2 acc[C];
#pragma unroll
    for (int r = 0; r < C; ++r) acc[r] = make_float2(0.f, 0.f);
    float2 w0 = *reinterpret_cast<const float2*>(wb);
    float2 w1 = *reinterpret_cast<const float2*>(wb + 256);
    float2 w2 = *reinterpret_cast<const float2*>(wb + 512);
    float2 w3 = *reinterpret_cast<const float2*>(wb + 768);
#pragma unroll 1
    for (int blk = 0; blk < 8; ++blk) {
      const float* wn = wb + 4 * ((blk < 7) ? blk + 1 : 7) * 256;
      const float2 n0 = *reinterpret_cast<const float2*>(wn);
      const float2 n1 = *reinterpret_cast<const float2*>(wn + 256);
      const float2 n2 = *reinterpret_cast<const float2*>(wn + 512);
      const float2 n3 = *reinterpret_cast<const float2*>(wn + 768);
#pragma unroll
      for (int r = 0; r < C; ++r) {
        const float4 z = *reinterpret_cast<const float4*>(zb + r * zstr + 4 * blk);
        acc[r].x = fmaf(z.x,w0.x, fmaf(z.y,w1.x, fmaf(z.z,w2.x, fmaf(z.w,w3.x, acc[r].x))));
        acc[r].y = fmaf(z.x,w0.y, fmaf(z.y,w1.y, fmaf(z.z,w2.y, fmaf(z.w,w3.y, acc[r].y))));
      }
      w0 = n0; w1 = n1; w2 = n2; w3 = n3;
    }
#pragma unroll
    for (int r = 0; r < C; ++r)
      *reinterpret_cast<float2*>(red + (kg * C + r) * 256 + c1) = acc[r];
  }
  __syncthreads();
  // ---------- reduce1 + bias (+lab) + relu -> h ----------
  if (t < 128 * C) {
    const int r  = t >> 7;
    const int c0 = 2 * (t & 127);
    float2 s = *reinterpret_cast<const float2*>(B1 + c0);
    if (uselab) {
      const int j = u1h[done + r] & 1;
      const float2 lv = *reinterpret_cast<const float2*>(lab + j * 256 + c0);
      s.x += lv.x; s.y += lv.y;
    }
#pragma unroll
    for (int q = 0; q < 8; ++q) {
      const float2 p = *reinterpret_cast<const float2*>(red + (q * C + r) * 256 + c0);
      s.x += p.x; s.y += p.y;
    }
    s.x = fmaxf(s.x, 0.f); s.y = fmaxf(s.y, 0.f);
    *reinterpret_cast<float2*>(h + r * 256 + c0) = s;
  }
  __syncthreads();
  // ---------- layer 2 ----------
  {
    const int c2 = 2 * ln;
    const float* wb2 = W2 + 16 * wv * 128 + c2;
    float2 acc[C];
#pragma unroll
    for (int r = 0; r < C; ++r) acc[r] = make_float2(0.f, 0.f);
    float2 w0 = *reinterpret_cast<const float2*>(wb2);
    float2 w1 = *reinterpret_cast<const float2*>(wb2 + 128);
    float2 w2 = *reinterpret_cast<const float2*>(wb2 + 256);
    float2 w3 = *reinterpret_cast<const float2*>(wb2 + 384);
#pragma unroll 1
    for (int blk = 0; blk < 4; ++blk) {
      const float* wn = wb2 + 4 * ((blk < 3) ? blk + 1 : 3) * 128;
      const float2 n0 = *reinterpret_cast<const float2*>(wn);
      const float2 n1 = *reinterpret_cast<const float2*>(wn + 128);
      const float2 n2 = *reinterpret_cast<const float2*>(wn + 256);
      const float2 n3 = *reinterpret_cast<const float2*>(wn + 384);
#pragma unroll
      for (int r = 0; r < C; ++r) {
        const float4 hv = *reinterpret_cast<const float4*>(h + r * 256 + 16 * wv + 4 * blk);
        acc[r].x = fmaf(hv.x,w0.x, fmaf(hv.y,w1.x, fmaf(hv.z,w2.x, fmaf(hv.w,w3.x, acc[r].x))));
        acc[r].y = fmaf(hv.x,w0.y, fmaf(hv.y,w1.y, fmaf(hv.z,w2.y, fmaf(hv.w,w3.y, acc[r].y))));
      }
      w0 = n0; w1 = n1; w2 = n2; w3 = n3;
    }
#pragma unroll
    for (int r = 0; r < C; ++r)
      *reinterpret_cast<float2*>(red + (wv * C + r) * 128 + c2) = acc[r];
  }
  __syncthreads();
  // ---------- reduce2 + bias -> eout ----------
  if (t < 64 * C) {
    const int r  = t >> 6;
    const int c0 = 2 * (t & 63);
    float2 s = *reinterpret_cast<const float2*>(B2 + c0);
#pragma unroll
    for (int q = 0; q < 16; ++q) {
      const float2 p = *reinterpret_cast<const float2*>(red + (q * C + r) * 128 + c0);
      s.x += p.x; s.y += p.y;
    }
    *reinterpret_cast<float2*>(eout + r * 128 + c0) = s;
  }
  __syncthreads();
}

// ---- paired MLP chunk (levels 1..3 non-uniform): 16 rows as TWO independent
// C8 chunks across wave groups (R13-proven). R16: each layer runs as TWO
// PASSES of 4 rows (acc[4], <=16 z regs in flight; live ~40) — kills the
// ~58 MB/dispatch scratch spill the 8-row unroll caused (z-hoist blew the
// 64-VGPR budget). Pass 2 re-reads the same weights from L1 (just streamed,
// ~16 KB working set). Bit-exact: same per-row FMA chains, same red layout.
__device__ __forceinline__ void mlp_pair(
    const float* zl,
    const float* __restrict__ W1, const float* __restrict__ B1,
    const float* __restrict__ W2, const float* __restrict__ B2,
    const float* lab, bool uselab, const short* u1h, int done,
    float* red, float* h, float* eout)
{
  const int t  = threadIdx.x;
  const int wv = t >> 6;
  const int ln = t & 63;
  const int g  = wv >> 3;                        // wave group = chunk
  // ---------- layer 1: per group 4 kg x 2 halves; 2 passes x 4 rows ------
  {
    const int kq = (wv >> 1) & 3;                // 64 k each
    const int c1 = (wv & 1) * 128 + 2 * ln;
    const float* wb = W1 + 64 * kq * 256 + c1;
#pragma unroll 1
    for (int pass = 0; pass < 2; ++pass) {
      const float* zb = zl + (g * 8 + pass * 4) * 256 + 64 * kq;
      float2 acc[4];
#pragma unroll
      for (int r = 0; r < 4; ++r) acc[r] = make_float2(0.f, 0.f);
      float2 w0 = *reinterpret_cast<const float2*>(wb);
      float2 w1 = *reinterpret_cast<const float2*>(wb + 256);
      float2 w2 = *reinterpret_cast<const float2*>(wb + 512);
      float2 w3 = *reinterpret_cast<const float2*>(wb + 768);
#pragma unroll 1
      for (int blk = 0; blk < 16; ++blk) {       // 16 x 4 k
        const float* wn = wb + 4 * ((blk < 15) ? blk + 1 : 15) * 256;
        const float2 n0 = *reinterpret_cast<const float2*>(wn);
        const float2 n1 = *reinterpret_cast<const float2*>(wn + 256);
        const float2 n2 = *reinterpret_cast<const float2*>(wn + 512);
        const float2 n3 = *reinterpret_cast<const float2*>(wn + 768);
#pragma unroll
        for (int r = 0; r < 4; ++r) {
          const float4 z = *reinterpret_cast<const float4*>(zb + r * 256 + 4 * blk);
          acc[r].x = fmaf(z.x,w0.x, fmaf(z.y,w1.x, fmaf(z.z,w2.x, fmaf(z.w,w3.x, acc[r].x))));
          acc[r].y = fmaf(z.x,w0.y, fmaf(z.y,w1.y, fmaf(z.z,w2.y, fmaf(z.w,w3.y, acc[r].y))));
        }
        w0 = n0; w1 = n1; w2 = n2; w3 = n3;
      }
#pragma unroll
      for (int r = 0; r < 4; ++r)
        *reinterpret_cast<float2*>(red + ((g * 4 + kq) * 8 + pass * 4 + r) * 256 + c1) = acc[r];
    }
  }
  __syncthreads();
  // ---------- reduce1 + bias (+lab) + relu -> h (16 rows) ----------
  for (int idx = t; idx < 2048; idx += NTHR) {
    const int r16 = idx >> 7;
    const int c0  = 2 * (idx & 127);
    const int gg = r16 >> 3, rr = r16 & 7;
    float2 s = *reinterpret_cast<const float2*>(B1 + c0);
    if (uselab) {
      const int j = u1h[done + r16] & 1;
      const float2 lv = *reinterpret_cast<const float2*>(lab + j * 256 + c0);
      s.x += lv.x; s.y += lv.y;
    }
#pragma unroll
    for (int q = 0; q < 4; ++q) {
      const float2 p = *reinterpret_cast<const float2*>(red + ((gg * 4 + q) * 8 + rr) * 256 + c0);
      s.x += p.x; s.y += p.y;
    }
    s.x = fmaxf(s.x, 0.f); s.y = fmaxf(s.y, 0.f);
    *reinterpret_cast<float2*>(h + r16 * 256 + c0) = s;
  }
  __syncthreads();
  // ---------- layer 2: per group 8 kg x 32 k; 2 passes x 4 rows ----------
  {
    const int kq = wv & 7;
    const int c2 = 2 * ln;
    const float* wb2 = W2 + 32 * kq * 128 + c2;
#pragma unroll 1
    for (int pass = 0; pass < 2; ++pass) {
      const float* hb = h + (g * 8 + pass * 4) * 256 + 32 * kq;
      float2 acc[4];
#pragma unroll
      for (int r = 0; r < 4; ++r) acc[r] = make_float2(0.f, 0.f);
      float2 w0 = *reinterpret_cast<const float2*>(wb2);
      float2 w1 = *reinterpret_cast<const float2*>(wb2 + 128);
      float2 w2 = *reinterpret_cast<const float2*>(wb2 + 256);
      float2 w3 = *reinterpret_cast<const float2*>(wb2 + 384);
#pragma unroll 1
      for (int blk = 0; blk < 8; ++blk) {        // 8 x 4 k
        const float* wn = wb2 + 4 * ((blk < 7) ? blk + 1 : 7) * 128;
        const float2 n0 = *reinterpret_cast<const float2*>(wn);
        const float2 n1 = *reinterpret_cast<const float2*>(wn + 128);
        const float2 n2 = *reinterpret_cast<const float2*>(wn + 256);
        const float2 n3 = *reinterpret_cast<const float2*>(wn + 384);
#pragma unroll
        for (int r = 0; r < 4; ++r) {
          const float4 hv = *reinterpret_cast<const float4*>(hb + r * 256 + 4 * blk);
          acc[r].x = fmaf(hv.x,w0.x, fmaf(hv.y,w1.x, fmaf(hv.z,w2.x, fmaf(hv.w,w3.x, acc[r].x))));
          acc[r].y = fmaf(hv.x,w0.y, fmaf(hv.y,w1.y, fmaf(hv.z,w2.y, fmaf(hv.w,w3.y, acc[r].y))));
        }
        w0 = n0; w1 = n1; w2 = n2; w3 = n3;
      }
#pragma unroll
      for (int r = 0; r < 4; ++r)
        *reinterpret_cast<float2*>(red + (wv * 8 + pass * 4 + r) * 128 + c2) = acc[r];
    }
  }
  __syncthreads();
  // ---------- reduce2 + bias -> eout (16 rows) ----------
  {
    const int r16 = t >> 6;
    const int c0  = 2 * (t & 63);
    const int gg = r16 >> 3, rr = r16 & 7;
    float2 s = *reinterpret_cast<const float2*>(B2 + c0);
#pragma unroll
    for (int q = 0; q < 8; ++q) {
      const float2 p = *reinterpret_cast<const float2*>(red + ((gg * 8 + q) * 8 + rr) * 128 + c0);
      s.x += p.x; s.y += p.y;
    }
    *reinterpret_cast<float2*>(eout + r16 * 128 + c0) = s;
  }
  __syncthreads();
}

// ---- fused check+speculative-bit chunk, l5 (R=4), contiguous z ----
template <int R>
__device__ __forceinline__ void fused_chunk(
    const float* zl,
    const float* __restrict__ Wc1_, const float* __restrict__ Bc1_,
    const float* __restrict__ Wc2_, const float* __restrict__ Bc2_,
    const float* __restrict__ Wb1_, const float* __restrict__ Bb1_,
    const float* __restrict__ Wb2_, const float* __restrict__ Bb2_,
    const float* lab,
    float* red, float* h, float* eout, float* spec)
{
  const int t  = threadIdx.x;
  const int wv = t >> 6;
  const int ln = t & 63;
  // ---------- layer 1: 8 kg x 2 col-halves; 2R partial rows ----------
  {
    const int kg = wv >> 1;
    const int c1 = (wv & 1) * 128 + 2 * ln;
    const float* wcb = Wc1_ + 32 * kg * 256 + c1;
    const float* wbb = Wb1_ + 32 * kg * 256 + c1;
    const float* zb  = zl + 32 * kg;
    float2 ac[R], ab[R];
#pragma unroll
    for (int r = 0; r < R; ++r) { ac[r] = make_float2(0.f,0.f); ab[r] = make_float2(0.f,0.f); }
    float2 c0 = *reinterpret_cast<const float2*>(wcb);
    float2 c1v = *reinterpret_cast<const float2*>(wcb + 256);
    float2 c2v = *reinterpret_cast<const float2*>(wcb + 512);
    float2 c3v = *reinterpret_cast<const float2*>(wcb + 768);
    float2 b0 = *reinterpret_cast<const float2*>(wbb);
    float2 b1 = *reinterpret_cast<const float2*>(wbb + 256);
    float2 b2 = *reinterpret_cast<const float2*>(wbb + 512);
    float2 b3 = *reinterpret_cast<const float2*>(wbb + 768);
#pragma unroll 1
    for (int blk = 0; blk < 8; ++blk) {
      const int nb = 4 * ((blk < 7) ? blk + 1 : 7);
      const float* wcn = wcb + nb * 256;
      const float* wbn = wbb + nb * 256;
      const float2 nc0 = *reinterpret_cast<const float2*>(wcn);
      const float2 nc1 = *reinterpret_cast<const float2*>(wcn + 256);
      const float2 nc2 = *reinterpret_cast<const float2*>(wcn + 512);
      const float2 nc3 = *reinterpret_cast<const float2*>(wcn + 768);
      const float2 nb0 = *reinterpret_cast<const float2*>(wbn);
      const float2 nb1 = *reinterpret_cast<const float2*>(wbn + 256);
      const float2 nb2 = *reinterpret_cast<const float2*>(wbn + 512);
      const float2 nb3 = *reinterpret_cast<const float2*>(wbn + 768);
#pragma unroll
      for (int r = 0; r < R; ++r) {
        const float4 z = *reinterpret_cast<const float4*>(zb + r * 256 + 4 * blk);
        ac[r].x = fmaf(z.x,c0.x, fmaf(z.y,c1v.x, fmaf(z.z,c2v.x, fmaf(z.w,c3v.x, ac[r].x))));
        ac[r].y = fmaf(z.x,c0.y, fmaf(z.y,c1v.y, fmaf(z.z,c2v.y, fmaf(z.w,c3v.y, ac[r].y))));
        ab[r].x = fmaf(z.x,b0.x, fmaf(z.y,b1.x, fmaf(z.z,b2.x, fmaf(z.w,b3.x, ab[r].x))));
        ab[r].y = fmaf(z.x,b0.y, fmaf(z.y,b1.y, fmaf(z.z,b2.y, fmaf(z.w,b3.y, ab[r].y))));
      }
      c0 = nc0; c1v = nc1; c2v = nc2; c3v = nc3;
      b0 = nb0; b1 = nb1; b2 = nb2; b3 = nb3;
    }
#pragma unroll
    for (int r = 0; r < R; ++r) {
      *reinterpret_cast<float2*>(red + (kg * 2 * R + r) * 256 + c1) = ac[r];
      *reinterpret_cast<float2*>(red + (kg * 2 * R + R + r) * 256 + c1) = ab[r];
    }
  }
  __syncthreads();
  // ---------- reduce1 -> h: 3R rows ----------
  for (int idx = t; idx < 3 * R * 128; idx += NTHR) {
    const int r  = idx >> 7;
    const int c0 = 2 * (idx & 127);
    const int pr = (r < 2 * R) ? r : r - R;
    float2 s;
    if (r < R) {
      s = *reinterpret_cast<const float2*>(Bc1_ + c0);
    } else {
      s = *reinterpret_cast<const float2*>(Bb1_ + c0);
      const float2 lv = *reinterpret_cast<const float2*>(lab + ((r < 2 * R) ? 0 : 256) + c0);
      s.x += lv.x; s.y += lv.y;
    }
#pragma unroll
    for (int q = 0; q < 8; ++q) {
      const float2 p = *reinterpret_cast<const float2*>(red + (q * 2 * R + pr) * 256 + c0);
      s.x += p.x; s.y += p.y;
    }
    s.x = fmaxf(s.x, 0.f); s.y = fmaxf(s.y, 0.f);
    *reinterpret_cast<float2*>(h + r * 256 + c0) = s;
  }
  __syncthreads();
  // ---------- layer 2: 8 kg x 2 col-halves (1 col/lane); 3R rows ----------
  {
    const int kg = wv >> 1;
    const int c2 = (wv & 1) * 64 + ln;
    const float* wcb = Wc2_ + 32 * kg * 128 + c2;
    const float* wbb = Wb2_ + 32 * kg * 128 + c2;
    float acc[3 * R];
#pragma unroll
    for (int r = 0; r < 3 * R; ++r) acc[r] = 0.f;
    float c0v = wcb[0], c1v = wcb[128], c2v = wcb[256], c3v = wcb[384];
    float b0v = wbb[0], b1v = wbb[128], b2v = wbb[256], b3v = wbb[384];
#pragma unroll 1
    for (int blk = 0; blk < 8; ++blk) {
      const int nb = 4 * ((blk < 7) ? blk + 1 : 7);
      const float* wcn = wcb + nb * 128;
      const float* wbn = wbb + nb * 128;
      const float nc0 = wcn[0], nc1 = wcn[128], nc2 = wcn[256], nc3 = wcn[384];
      const float nb0 = wbn[0], nb1 = wbn[128], nb2 = wbn[256], nb3 = wbn[384];
      const float* hb = h + 32 * kg + 4 * blk;
#pragma unroll
      for (int r = 0; r < 3 * R; ++r) {
        const float4 hv = *reinterpret_cast<const float4*>(hb + r * 256);
        if (r < R)
          acc[r] = fmaf(hv.x,c0v, fmaf(hv.y,c1v, fmaf(hv.z,c2v, fmaf(hv.w,c3v, acc[r]))));
        else
          acc[r] = fmaf(hv.x,b0v, fmaf(hv.y,b1v, fmaf(hv.z,b2v, fmaf(hv.w,b3v, acc[r]))));
      }
      c0v = nc0; c1v = nc1; c2v = nc2; c3v = nc3;
      b0v = nb0; b1v = nb1; b2v = nb2; b3v = nb3;
    }
#pragma unroll
    for (int r = 0; r < 3 * R; ++r)
      red[(kg * 3 * R + r) * 128 + c2] = acc[r];
  }
  __syncthreads();
  // ---------- reduce2: check -> eout, bit -> spec[2][R][128] ----------
  for (int idx = t; idx < 3 * R * 128; idx += NTHR) {
    const int r = idx >> 7;
    const int c = idx & 127;
    float s = (r < R) ? Bc2_[c] : Bb2_[c];
#pragma unroll
    for (int q = 0; q < 8; ++q) s += red[(q * 3 * R + r) * 128 + c];
    if (r < R)            eout[r * 128 + c] = s;
    else if (r < 2 * R)   spec[(r - R) * 128 + c] = s;
    else                  spec[R * 128 + (r - 2 * R) * 128 + c] = s;
  }
  __syncthreads();
}

__global__ void sc_setup(const int* __restrict__ info_set,
                         const float* __restrict__ E_obs,
                         const float* __restrict__ E_lab,
                         const float* __restrict__ Wb1,
                         const float* __restrict__ Wc2, const float* __restrict__ bc2,
                         const float* __restrict__ Wb2, const float* __restrict__ bb2,
                         const float* __restrict__ Wl, const float* __restrict__ bl,
                         int* __restrict__ pos2k, float* __restrict__ lab1,
                         float* __restrict__ eroot, float* __restrict__ cvb)
{
  const int t = threadIdx.x;   // 256 threads
  pos2k[t] = -1;
  __syncthreads();
  if (t < 128) pos2k[info_set[t]] = t;
  eroot[t] = E_obs[2 * 128 + (t & 127)];
  for (int j = 0; j < 2; ++j) {
    float s = 0.0f;
    for (int k = 0; k < 128; ++k)
      s = fmaf(E_lab[j * 128 + k], Wb1[(256 + k) * 256 + t], s);
    lab1[j * 256 + t] = s;
  }
  {
    float sc = 0.f, sb = 0.f;
    for (int c = 0; c < 128; ++c) {
      sc = fmaf(Wc2[t * 128 + c], Wl[c], sc);
      sb = fmaf(Wb2[t * 128 + c], Wl[c], sb);
    }
    cvb[t] = sc;
    cvb[256 + t] = sb;
  }
  if (t == 0) {
    float s = bl[0];
    for (int c = 0; c < 128; ++c) s = fmaf(bc2[c], Wl[c], s);
    cvb[512] = s;
  }
  if (t == 1) {
    float s = bl[0];
    for (int c = 0; c < 128; ++c) s = fmaf(bb2[c], Wl[c], s);
    cvb[513] = s;
  }
}

__global__ __launch_bounds__(NTHR)
__attribute__((amdgpu_waves_per_eu(4, 4)))
void sc_main(const int* __restrict__ info_bits, const float* __restrict__ rin,
             const float* __restrict__ Wc1, const float* __restrict__ bc1,
             const float* __restrict__ Wc2, const float* __restrict__ bc2,
             const float* __restrict__ Wb1, const float* __restrict__ bb1,
             const float* __restrict__ Wb2, const float* __restrict__ bb2,
             const int* __restrict__ pos2k, const float* __restrict__ lab1_g,
             const float* __restrict__ eroot_g, const float* __restrict__ cvb_g,
             float* __restrict__ wsall, float* __restrict__ out)
{
  const int b = blockIdx.x;
  const int t = threadIdx.x;
  float* e1g = wsall + (size_t)b * EG_STRIDE;      // level-1 e (global)

  __shared__ __align__(16) float red[16384];       // 64 KB; tail [12288,16384) =
                                                   //   l6 right-variant half-sums
  __shared__ __align__(16) float h_lds[4096];      // 16 KB hidden (16 rows) / z-stage
  __shared__ __align__(16) float scratch[1536];    //  6 KB: lvl-0 out UNION specs
  __shared__ __align__(16) float e2[8192];         // 32 KB level-2 e
  __shared__ __align__(16) float e3[4096];         // 16 KB level-3 e
  __shared__ __align__(16) float e4[2048];         //  8 KB level-4 e
  __shared__ __align__(16) float e567[1792];       // levels 5..7: 8,4,2 rows
  __shared__ __align__(16) float lab_lds[512];
  __shared__ __align__(16) float eroot[256];
  __shared__ __align__(16) float cvb_lds[516];     // cv|bv|cc|cb
  __shared__ __align__(16) float bias_lds[512];    // bc1|bb1
  __shared__ float rrow[256];
  __shared__ short xh[520];
  __shared__ short ibits[128];
  __shared__ short p2k_l[256];

  float* xO = out;
  float* fO = out + 32768;
  float* uO = out + 65536;
  float* pO = out + 98304;
  float* rO = out + 131072;

  // ---- prologue ----
  if (t < 512) lab_lds[t] = lab1_g[t];
  if (t < 514) cvb_lds[t] = cvb_g[t];
  if (t < 256) bias_lds[t] = bc1[t];
  else if (t < 512) bias_lds[256 + (t - 256)] = bb1[t - 256];
  if (t < 256) {
    eroot[t]  = eroot_g[t];
    p2k_l[t]  = (short)pos2k[t];
    const float rv = rin[b * 256 + t];
    rrow[t]   = rv;
    rO[b * 256 + t] = rv;
    fO[b * 256 + t] = (pos2k[t] >= 0) ? 2.0f : 1.0f;
  }
  if (t < 128) ibits[t] = (short)info_bits[b * 128 + t];
  if (t == 0) { xh[512] = 0; xh[513] = 1; }        // constant u1h for lvl-0 bit
  __syncthreads();

  // ---- uniform-first-descent flag (R15-proven): e1g must STILL be written
  // by l0-check — the l1-bit visit at i=62 stages left-e1 from e1g. ----
  bool fdesc = true;

  // ---- levels 1..4 ----
  auto run_level = [&](int l, bool isbit) {
    const float* W1 = isbit ? Wb1 : Wc1;
    const float* B1 = isbit ? bb1 : bc1;
    const float* W2 = isbit ? Wb2 : Wc2;
    const float* B2 = isbit ? bb2 : bc2;
    const short* u1h = xh + xoff(l);
    if (!isbit && fdesc) {            // uniform descent: C1 + broadcast
      const float* zu; float* eo; int bsz;
      switch (l) {
        case 1:  zu = scratch; eo = e2;   bsz = 8192; break;
        case 2:  zu = e2;      eo = e3;   bsz = 4096; break;
        case 3:  zu = e3;      eo = e4;   bsz = 2048; break;
        default: zu = e4;      eo = e567; bsz = 1024; break;   // l == 4
      }
      mlp_chunk<1>(zu, 0, W1, B1, W2, B2, lab_lds, false, u1h, 0,
                   red, h_lds, eo);
      for (int idx = t + 128; idx < bsz; idx += NTHR) eo[idx] = eo[idx & 127];
      __syncthreads();
      return;
    }
    if (l == 4) {
      mlp_chunk<8>(e4, 256, W1, B1, W2, B2, lab_lds, isbit, u1h, 0,
                   red, h_lds, e567);
      return;
    }
    const int rows = 128 >> l;
    const float* ein; float* eo;
    switch (l) {
      case 1:  ein = nullptr; eo = e2; break;
      case 2:  ein = e2;      eo = e3; break;
      default: ein = e3;      eo = e4; break;      // l == 3
    }
    for (int done = 0; done < rows; done += 16) {
      const float* zl;
      if (l == 1) {   // stage 16 rows into h_lds (dead until reduce1 rewrites)
        const float4* src = reinterpret_cast<const float4*>(e1g + done * 256);
        for (int i4 = t; i4 < 1024; i4 += NTHR)
          reinterpret_cast<float4*>(h_lds)[i4] = src[i4];
        __syncthreads();
        zl = h_lds;
      } else {
        zl = ein + done * 256;
      }
      mlp_pair(zl, W1, B1, W2, B2, lab_lds, isbit, u1h, done,
               red, h_lds, eo + done * 128);
    }
  };

  // ---- level 0 special: check = C1; output duplicated in scratch[0:256)
  // for the uniform l1 read AND broadcast to e1g (R14 lesson: the l1-bit
  // visit at i=62 precedes l0-bit and stages from e1g). ----
  auto run_level0 = [&](bool isbit) {
    if (!isbit) {
      mlp_chunk<1>(eroot, 0, Wc1, bc1, Wc2, bc2, lab_lds, false, xh, 0, red, h_lds, scratch);
      if (t < 128) scratch[128 + t] = scratch[t];
      for (int i4 = t; i4 < 4096; i4 += NTHR)
        reinterpret_cast<float4*>(e1g)[i4] =
            reinterpret_cast<const float4*>(scratch)[i4 & 31];
      __syncthreads();
    } else {
      mlp_chunk<2>(eroot, 0, Wb1, bb1, Wb2, bb2, lab_lds, true, xh + 512, 0, red, h_lds, scratch);
      for (int i4 = t; i4 < 4096; i4 += NTHR)
        reinterpret_cast<float4*>(e1g)[i4] =
            reinterpret_cast<const float4*>(scratch)[(xh[i4 >> 5] & 1) * 32 + (i4 & 31)];
      __syncthreads();
    }
  };

  // ---- shared l6 tail: layer2 (6 h rows) + reduce2 -> e7 + spec6 ----
  auto l6_tail = [&]() {
    const int wv = t >> 6;
    const int ln = t & 63;
    {
      const int kg = wv >> 1;
      const int c2 = (wv & 1) * 64 + ln;
      const float* wcb = Wc2 + 32 * kg * 128 + c2;
      const float* wbb = Wb2 + 32 * kg * 128 + c2;
      float acc[6];
#pragma unroll
      for (int r = 0; r < 6; ++r) acc[r] = 0.f;
      float c0v = wcb[0], c1v = wcb[128], c2v = wcb[256], c3v = wcb[384];
      float b0v = wbb[0], b1v = wbb[128], b2v = wbb[256], b3v = wbb[384];
#pragma unroll 1
      for (int blk = 0; blk < 8; ++blk) {
        const int nb = 4 * ((blk < 7) ? blk + 1 : 7);
        const float* wcn = wcb + nb * 128;
        const float* wbn = wbb + nb * 128;
        const float nc0 = wcn[0], nc1 = wcn[128], nc2 = wcn[256], nc3 = wcn[384];
        const float nb0 = wbn[0], nb1 = wbn[128], nb2 = wbn[256], nb3 = wbn[384];
        const float* hb = h_lds + 32 * kg + 4 * blk;
#pragma unroll
        for (int r = 0; r < 6; ++r) {
          const float4 hv = *reinterpret_cast<const float4*>(hb + r * 256);
          if (r < 2)
            acc[r] = fmaf(hv.x,c0v, fmaf(hv.y,c1v, fmaf(hv.z,c2v, fmaf(hv.w,c3v, acc[r]))));
          else
            acc[r] = fmaf(hv.x,b0v, fmaf(hv.y,b1v, fmaf(hv.z,b2v, fmaf(hv.w,b3v, acc[r]))));
        }
        c0v = nc0; c1v = nc1; c2v = nc2; c3v = nc3;
        b0v = nb0; b1v = nb1; b2v = nb2; b3v = nb3;
      }
#pragma unroll
      for (int r = 0; r < 6; ++r)
        red[(kg * 6 + r) * 128 + c2] = acc[r];
    }
    __syncthreads();
    if (t < 768) {
      const int r = t >> 7;
      const int c = t & 127;
      float s = (r < 2) ? bc2[c] : bb2[c];
#pragma unroll
      for (int q = 0; q < 8; ++q) s += red[(q * 6 + r) * 128 + c];
      float* e7 = e567 + 1536;
      float* spec6 = scratch + 1024;
      if (r < 2)        e7[r * 128 + c] = s;
      else if (r < 4)   spec6[(r - 2) * 128 + c] = s;
      else              spec6[256 + (r - 4) * 128 + c] = s;
    }
    __syncthreads();
  };

  // ---- f6-LEFT (R12-proven): one Wc1+Wb1 stream serves this exec AND the
  // later f6-RIGHT via red-tail half-sums. ----
  auto run_f6_left = [&]() {
    const int wv = t >> 6;
    const int ln = t & 63;
    {
      const int kg  = wv >> 2;
      const int col = (wv & 3) * 64 + ln;
      const float* wcb = Wc1 + 64 * kg * 256 + col;
      const float* wbb = Wb1 + 64 * kg * 256 + col;
      const float* zL  = e567 + 1024 + 64 * kg;
      const int rrofs = (kg >> 1) * 128 + (kg & 1) * 64;
      float aLc0 = 0.f, aLc1 = 0.f, aLb0 = 0.f, aLb1 = 0.f;
      float aRc[4], aRb[4];
#pragma unroll
      for (int q = 0; q < 4; ++q) { aRc[q] = 0.f; aRb[q] = 0.f; }
      float wc0 = wcb[0], wc1 = wcb[256], wc2 = wcb[512], wc3 = wcb[768];
      float wb0 = wbb[0], wb1 = wbb[256], wb2 = wbb[512], wb3 = wbb[768];
#pragma unroll 1
      for (int blk = 0; blk < 16; ++blk) {
        const float* wcn = wcb + 4 * ((blk < 15) ? blk + 1 : 15) * 256;
        const float* wbn = wbb + 4 * ((blk < 15) ? blk + 1 : 15) * 256;
        const float nc0 = wcn[0], nc1 = wcn[256], nc2 = wcn[512], nc3 = wcn[768];
        const float nb0 = wbn[0], nb1 = wbn[256], nb2 = wbn[512], nb3 = wbn[768];
        {
          const float4 z = *reinterpret_cast<const float4*>(zL + 4 * blk);
          aLc0 = fmaf(z.x,wc0, fmaf(z.y,wc1, fmaf(z.z,wc2, fmaf(z.w,wc3, aLc0))));
          aLb0 = fmaf(z.x,wb0, fmaf(z.y,wb1, fmaf(z.z,wb2, fmaf(z.w,wb3, aLb0))));
        }
        {
          const float4 z = *reinterpret_cast<const float4*>(zL + 256 + 4 * blk);
          aLc1 = fmaf(z.x,wc0, fmaf(z.y,wc1, fmaf(z.z,wc2, fmaf(z.w,wc3, aLc1))));
          aLb1 = fmaf(z.x,wb0, fmaf(z.y,wb1, fmaf(z.z,wb2, fmaf(z.w,wb3, aLb1))));
        }
#pragma unroll
        for (int r = 0; r < 2; ++r) {
#pragma unroll
          for (int v = 0; v < 2; ++v) {
            const float4 z = *reinterpret_cast<const float4*>(
                scratch + v * 512 + 2 * r * 128 + rrofs + 4 * blk);
            aRc[r * 2 + v] = fmaf(z.x,wc0, fmaf(z.y,wc1, fmaf(z.z,wc2, fmaf(z.w,wc3, aRc[r * 2 + v]))));
            aRb[r * 2 + v] = fmaf(z.x,wb0, fmaf(z.y,wb1, fmaf(z.z,wb2, fmaf(z.w,wb3, aRb[r * 2 + v]))));
          }
        }
        wc0 = nc0; wc1 = nc1; wc2 = nc2; wc3 = nc3;
        wb0 = nb0; wb1 = nb1; wb2 = nb2; wb3 = nb3;
      }
      red[(kg * 12 + 0) * 256 + col] = aLc0;
      red[(kg * 12 + 1) * 256 + col] = aLc1;
      red[(kg * 12 + 2) * 256 + col] = aLb0;
      red[(kg * 12 + 3) * 256 + col] = aLb1;
#pragma unroll
      for (int q = 0; q < 4; ++q) {
        red[(kg * 12 + 4 + q) * 256 + col] = aRc[q];
        red[(kg * 12 + 8 + q) * 256 + col] = aRb[q];
      }
    }
    __syncthreads();
    for (int idx = t; idx < 1536; idx += NTHR) {
      const int r6  = idx >> 8;
      const int col = idx & 255;
      const int pr  = (r6 < 2) ? r6 : 2 + ((r6 - 2) & 1);
      float s = (r6 < 2) ? bias_lds[col] : bias_lds[256 + col];
      if (r6 >= 2) s += lab_lds[((r6 >= 4) ? 256 : 0) + col];
#pragma unroll
      for (int q = 0; q < 4; ++q) s += red[(q * 12 + pr) * 256 + col];
      h_lds[r6 * 256 + col] = fmaxf(s, 0.f);
    }
    for (int idx = t; idx < 4096; idx += NTHR) {
      const int col  = idx & 255;
      const int q    = idx >> 8;
      const int v    = q & 1;
      const int half = (q >> 1) & 1;
      const int r    = (q >> 2) & 1;
      const int type = q >> 3;
      const int rowi = (type ? 8 : 4) + r * 2 + v;
      red[12288 + q * 256 + col] =
          red[((half * 2 + 0) * 12 + rowi) * 256 + col] +
          red[((half * 2 + 1) * 12 + rowi) * 256 + col];
    }
    __syncthreads();
    l6_tail();
  };

  auto run_f6_right = [&]() {
    for (int idx = t; idx < 1536; idx += NTHR) {
      const int r6  = idx >> 8;
      const int col = idx & 255;
      const int type = (r6 < 2) ? 0 : 1;
      const int r    = (r6 < 2) ? r6 : ((r6 - 2) & 1);
      const int v0 = xh[xoff(5) + 2 * r] & 1;
      const int v1 = xh[xoff(5) + 2 * r + 1] & 1;
      const int q0 = ((type * 2 + r) * 2 + 0) * 2 + v0;
      const int q1 = ((type * 2 + r) * 2 + 1) * 2 + v1;
      float s = red[12288 + q0 * 256 + col] + red[12288 + q1 * 256 + col];
      s += (type == 0) ? bias_lds[col] : bias_lds[256 + col];
      if (type) s += lab_lds[((r6 >= 4) ? 256 : 0) + col];
      h_lds[r6 * 256 + col] = fmaxf(s, 0.f);
    }
    __syncthreads();
    l6_tail();
  };

  // ---- shared leaf-decide (lane 0 of wave 0 only) ----
  auto decide_pair = [&](float d0, float d1, float d2, int i, int side) {
    int xv0, xv1;
    {
      const float p  = 1.0f / (1.0f + expf(-d0));
      const float rv = rrow[i];
      const int  hd     = (rv > p) ? 1 : 0;
      const bool frozen = fabsf(p - 0.5f) > 0.25f;
      const int  k  = p2k_l[i];
      const int  fc = (k >= 0) ? (int)ibits[k] : 2;
      xv0 = (fc == 2 || frozen) ? hd : fc;
      pO[b * 256 + i] = p;
      uO[b * 256 + i] = (float)xv0;
    }
    {
      const float dv = (xv0 & 1) ? d2 : d1;
      const float p  = 1.0f / (1.0f + expf(-dv));
      const float rv = rrow[i + 1];
      const int  hd     = (rv > p) ? 1 : 0;
      const bool frozen = fabsf(p - 0.5f) > 0.25f;
      const int  k  = p2k_l[i + 1];
      const int  fc = (k >= 0) ? (int)ibits[k] : 2;
      xv1 = (fc == 2 || frozen) ? hd : fc;
      pO[b * 256 + i + 1] = p;
      uO[b * 256 + i + 1] = (float)xv1;
    }
    const int base = xoff(6) + side * 2;
    xh[base]     = (short)(xv0 ^ xv1);
    xh[base + 1] = (short)xv1;
  };

  // ---- l7 LEFT: one weight stream serves both l7 pairs (R11-proven) ----
  auto run_l7_left = [&](const float* zh0, const float* zh1, int i) {
    const int wv = t >> 6;
    const int ln = t & 63;
    {
      const int kg = wv >> 1;
      const int c1 = (wv & 1) * 128 + 2 * ln;
      const float* wcb = Wc1 + 32 * kg * 256 + c1;
      const float* wbb = Wb1 + 32 * kg * 256 + c1;
      const float* zp = (kg >= 4) ? zh1 : zh0;
      const float* vA = scratch + 1024 + ((kg >= 4) ? 128 : 0);
      const int kb = 32 * (kg & 3);
      float2 acL = make_float2(0.f,0.f), abL = make_float2(0.f,0.f);
      float2 ac0 = make_float2(0.f,0.f), ab0 = make_float2(0.f,0.f);
      float2 ac1 = make_float2(0.f,0.f), ab1 = make_float2(0.f,0.f);
#pragma unroll 1
      for (int blk = 0; blk < 8; ++blk) {
        const float* wcp = wcb + 4 * blk * 256;
        const float* wbp = wbb + 4 * blk * 256;
        const float2 c0 = *reinterpret_cast<const float2*>(wcp);
        const float2 c1v = *reinterpret_cast<const float2*>(wcp + 256);
        const float2 c2v = *reinterpret_cast<const float2*>(wcp + 512);
        const float2 c3v = *reinterpret_cast<const float2*>(wcp + 768);
        const float2 b0 = *reinterpret_cast<const float2*>(wbp);
        const float2 b1 = *reinterpret_cast<const float2*>(wbp + 256);
        const float2 b2 = *reinterpret_cast<const float2*>(wbp + 512);
        const float2 b3 = *reinterpret_cast<const float2*>(wbp + 768);
        const float4 zL = *reinterpret_cast<const float4*>(zp + kb + 4 * blk);
        acL.x = fmaf(zL.x,c0.x, fmaf(zL.y,c1v.x, fmaf(zL.z,c2v.x, fmaf(zL.w,c3v.x, acL.x))));
        acL.y = fmaf(zL.x,c0.y, fmaf(zL.y,c1v.y, fmaf(zL.z,c2v.y, fmaf(zL.w,c3v.y, acL.y))));
        abL.x = fmaf(zL.x,b0.x, fmaf(zL.y,b1.x, fmaf(zL.z,b2.x, fmaf(zL.w,b3.x, abL.x))));
        abL.y = fmaf(zL.x,b0.y, fmaf(zL.y,b1.y, fmaf(zL.z,b2.y, fmaf(zL.w,b3.y, abL.y))));
        const float4 z0 = *reinterpret_cast<const float4*>(vA + kb + 4 * blk);
        ac0.x = fmaf(z0.x,c0.x, fmaf(z0.y,c1v.x, fmaf(z0.z,c2v.x, fmaf(z0.w,c3v.x, ac0.x))));
        ac0.y = fmaf(z0.x,c0.y, fmaf(z0.y,c1v.y, fmaf(z0.z,c2v.y, fmaf(z0.w,c3v.y, ac0.y))));
        ab0.x = fmaf(z0.x,b0.x, fmaf(z0.y,b1.x, fmaf(z0.z,b2.x, fmaf(z0.w,b3.x, ab0.x))));
        ab0.y = fmaf(z0.x,b0.y, fmaf(z0.y,b1.y, fmaf(z0.z,b2.y, fmaf(z0.w,b3.y, ab0.y))));
        const float4 z1 = *reinterpret_cast<const float4*>(vA + 256 + kb + 4 * blk);
        ac1.x = fmaf(z1.x,c0.x, fmaf(z1.y,c1v.x, fmaf(z1.z,c2v.x, fmaf(z1.w,c3v.x, ac1.x))));
        ac1.y = fmaf(z1.x,c0.y, fmaf(z1.y,c1v.y, fmaf(z1.z,c2v.y, fmaf(z1.w,c3v.y, ac1.y))));
        ab1.x = fmaf(z1.x,b0.x, fmaf(z1.y,b1.x, fmaf(z1.z,b2.x, fmaf(z1.w,b3.x, ab1.x))));
        ab1.y = fmaf(z1.x,b0.y, fmaf(z1.y,b1.y, fmaf(z1.z,b2.y, fmaf(z1.w,b3.y, ab1.y))));
      }
      *reinterpret_cast<float2*>(red + (kg * 6 + 0) * 256 + c1) = acL;
      *reinterpret_cast<float2*>(red + (kg * 6 + 1) * 256 + c1) = abL;
      *reinterpret_cast<float2*>(red + (kg * 6 + 2) * 256 + c1) = ac0;
      *reinterpret_cast<float2*>(red + (kg * 6 + 3) * 256 + c1) = ab0;
      *reinterpret_cast<float2*>(red + (kg * 6 + 4) * 256 + c1) = ac1;
      *reinterpret_cast<float2*>(red + (kg * 6 + 5) * 256 + c1) = ab1;
    }
    __syncthreads();
    if (t < 64) {
      float p0 = 0.f, p1 = 0.f, p2 = 0.f;
#pragma unroll
      for (int ii = 0; ii < 4; ++ii) {
        const int c = t + 64 * ii;
        float r0 = 0.f, r1 = 0.f;
#pragma unroll
        for (int q = 0; q < 8; ++q) {
          r0 += red[(q * 6 + 0) * 256 + c];
          r1 += red[(q * 6 + 1) * 256 + c];
        }
        const float s0 = fmaxf(bias_lds[c] + r0, 0.f);
        const float s1 = fmaxf(bias_lds[256 + c] + lab_lds[c] + r1, 0.f);
        const float s2 = fmaxf(bias_lds[256 + c] + lab_lds[256 + c] + r1, 0.f);
        const float vc = cvb_lds[c], vb = cvb_lds[256 + c];
        p0 = fmaf(s0, vc, p0); p1 = fmaf(s1, vb, p1); p2 = fmaf(s2, vb, p2);
      }
#pragma unroll
      for (int m = 32; m >= 1; m >>= 1) {
        p0 += __shfl_xor(p0, m); p1 += __shfl_xor(p1, m); p2 += __shfl_xor(p2, m);
      }
      if (t == 0)
        decide_pair(p0 + cvb_lds[512], p1 + cvb_lds[513], p2 + cvb_lds[513], i, 0);
    }
    __syncthreads();
  };

  auto run_l7_right = [&](int i, int side) {
    if (t < 64) {
      const int bit0 = xh[xoff(6) + 0] & 1;
      const int bit1 = xh[xoff(6) + 1] & 1;
      float p0 = 0.f, p1 = 0.f, p2 = 0.f;
#pragma unroll
      for (int ii = 0; ii < 4; ++ii) {
        const int c = t + 64 * ii;
        float r0 = 0.f, r1 = 0.f;
#pragma unroll
        for (int q = 0; q < 8; ++q) {
          const int vo = ((q < 4) ? bit0 : bit1) * 2;
          r0 += red[(q * 6 + 2 + vo) * 256 + c];
          r1 += red[(q * 6 + 3 + vo) * 256 + c];
        }
        const float s0 = fmaxf(bias_lds[c] + r0, 0.f);
        const float s1 = fmaxf(bias_lds[256 + c] + lab_lds[c] + r1, 0.f);
        const float s2 = fmaxf(bias_lds[256 + c] + lab_lds[256 + c] + r1, 0.f);
        const float vc = cvb_lds[c], vb = cvb_lds[256 + c];
        p0 = fmaf(s0, vc, p0); p1 = fmaf(s1, vb, p1); p2 = fmaf(s2, vb, p2);
      }
#pragma unroll
      for (int m = 32; m >= 1; m >>= 1) {
        p0 += __shfl_xor(p0, m); p1 += __shfl_xor(p1, m); p2 += __shfl_xor(p2, m);
      }
      if (t == 0)
        decide_pair(p0 + cvb_lds[512], p1 + cvb_lds[513], p2 + cvb_lds[513], i, side);
    }
    __syncthreads();
  };

  auto do_combine = [&](int l, int side) {
    const int n = 256 >> l, half = n >> 1;
    if (t < half) {
      const int u1 = xh[xoff(l) + t];
      const int u2 = xh[xoff(l) + half + t];
      if (l > 0) {
        const int base = xoff(l - 1) + side * n;
        xh[base + 2 * t]     = (short)(u1 ^ u2);
        xh[base + 2 * t + 1] = (short)u2;
      } else {
        xO[b * 256 + 2 * t]     = (float)(u1 ^ u2);
        xO[b * 256 + 2 * t + 1] = (float)u2;
      }
    }
    __syncthreads();
  };

  // ---- SC traversal ----
  const float* l7z0 = nullptr; const float* l7z1 = nullptr;
  bool l6left = true;
  int i = 0, l = 0;
  bool isbit = false;
  while (true) {
    if (l == 7) {
      fdesc = false;
      const int s2 = __builtin_ctz(i + 2);
      if ((i & 2) == 0) run_l7_left(l7z0, l7z1, i);
      else              run_l7_right(i, (1 < s2) ? 1 : 0);
      if (i == 254) {
        for (int j = 2; j <= 8; ++j) do_combine(8 - j, (j < 8) ? 1 : 0);
        break;
      }
      i += 2;
      for (int j = 2; j <= s2; ++j) do_combine(8 - j, (j < s2) ? 1 : 0);
      l = 7 - s2;
      isbit = true;
      continue;
    }
    if (l >= 5) {
      if (isbit) {
        if (l == 5) l6left = false;   // next f6 selects via xh bits (no stream)
      } else {
        if (l == 5) {
          fused_chunk<4>(e567, Wc1, bc1, Wc2, bc2, Wb1, bb1, Wb2, bb2, lab_lds,
                         red, h_lds, e567 + 1024, scratch);
          l6left = true;
        } else {          // l == 6
          if (l6left) run_f6_left();
          else        run_f6_right();
          l7z0 = e567 + 1536; l7z1 = e567 + 1536 + 128;
        }
      }
    } else if (l == 0) {
      run_level0(isbit);
    } else {
      run_level(l, isbit);
    }
    ++l; isbit = false;
  }
}

extern "C" void kernel_launch(void* const* d_in, const int* in_sizes, int n_in,
                              void* d_out, int out_size, void* d_ws, size_t ws_size,
                              hipStream_t stream)
{
  const int*   info_bits = (const int*)  d_in[0];
  const float* rin       = (const float*)d_in[1];
  const int*   info_set  = (const int*)  d_in[2];
  const float* E_obs     = (const float*)d_in[3];
  const float* E_lab     = (const float*)d_in[4];
  const float* Wc1 = (const float*)d_in[5];
  const float* bc1 = (const float*)d_in[6];
  const float* Wc2 = (const float*)d_in[7];
  const float* bc2 = (const float*)d_in[8];
  const float* Wb1 = (const float*)d_in[9];
  const float* bb1 = (const float*)d_in[10];
  const float* Wb2 = (const float*)d_in[11];
  const float* bb2 = (const float*)d_in[12];
  const float* Wl  = (const float*)d_in[13];
  const float* bl  = (const float*)d_in[14];

  int*   pos2k = (int*)d_ws;                 // [0,256) ints
  float* lab1  = (float*)d_ws + 256;         // [256,768)
  float* eroot = (float*)d_ws + 768;         // [768,1024)
  float* cvb   = (float*)d_ws + 1024;        // [1024,1538): cv|bv|cc|cb
  float* wsall = (float*)d_ws + 2048;        // 128 x EG_STRIDE floats

  hipLaunchKernelGGL(sc_setup, dim3(1), dim3(256), 0, stream,
                     info_set, E_obs, E_lab, Wb1, Wc2, bc2, Wb2, bb2,
                     Wl, bl, pos2k, lab1, eroot, cvb);
  hipLaunchKernelGGL(sc_main, dim3(128), dim3(NTHR), 0, stream,
                     info_bits, rin,
                     Wc1, bc1, Wc2, bc2, Wb1, bb1, Wb2, bb2,
                     pos2k, lab1, eroot, cvb, wsall, (float*)d_out);
}

// Round 17
// 2668.474 us; speedup vs baseline: 1.1933x; 1.1933x over previous
//
#include <hip/hip_runtime.h>
#include <math.h>

#define NTHR 1024

constexpr int EG_STRIDE = 16384;   // floats per batch: e1 only (128 rows x 128)

__device__ __forceinline__ int xoff(int l) { return 512 - (512 >> l); }   // l in 0..7

// ---- MLP chunk, C rows (l0, l4, uniform-descent C1): R3 register shape +
// DEPTH-1 prefetch (R10: depth-2 -> 330 MB spill; depth-1 is the ceiling).
// `#pragma unroll 1` on k-loops is load-bearing (R1/R2 spill lesson).
template <int C>
__device__ __forceinline__ void mlp_chunk(
    const float* zl, int zstr,
    const float* __restrict__ W1, const float* __restrict__ B1,
    const float* __restrict__ W2, const float* __restrict__ B2,
    const float* lab, bool uselab, const short* u1h, int done,
    float* red, float* h, float* eout)
{
  const int t  = threadIdx.x;
  const int wv = t >> 6;
  const int ln = t & 63;
  // ---------- layer 1 ----------
  {
    const int kg = wv >> 1;
    const int c1 = (wv & 1) * 128 + 2 * ln;
    const float* wb = W1 + 32 * kg * 256 + c1;
    const float* zb = zl + 32 * kg;
    float2 acc[C];
#pragma unroll
    for (int r = 0; r < C; ++r) acc[r] = make_float2(0.f, 0.f);
    float2 w0 = *reinterpret_cast<const float2*>(wb);
    float2 w1 = *reinterpret_cast<const float2*>(wb + 256);
    float2 w2 = *reinterpret_cast<const float2*>(wb + 512);
    float2 w3 = *reinterpret_cast<const float2*>(wb + 768);
#pragma unroll 1
    for (int blk = 0; blk < 8; ++blk) {
      const float* wn = wb + 4 * ((blk < 7) ? blk + 1 : 7) * 256;
      const float2 n0 = *reinterpret_cast<const float2*>(wn);
      const float2 n1 = *reinterpret_cast<const float2*>(wn + 256);
      const float2 n2 = *reinterpret_cast<const float2*>(wn + 512);
      const float2 n3 = *reinterpret_cast<const float2*>(wn + 768);
#pragma unroll
      for (int r = 0; r < C; ++r) {
        const float4 z = *reinterpret_cast<const float4*>(zb + r * zstr + 4 * blk);
        acc[r].x = fmaf(z.x,w0.x, fmaf(z.y,w1.x, fmaf(z.z,w2.x, fmaf(z.w,w3.x, acc[r].x))));
        acc[r].y = fmaf(z.x,w0.y, fmaf(z.y,w1.y, fmaf(z.z,w2.y, fmaf(z.w,w3.y, acc[r].y))));
      }
      w0 = n0; w1 = n1; w2 = n2; w3 = n3;
    }
#pragma unroll
    for (int r = 0; r < C; ++r)
      *reinterpret_cast<float2*>(red + (kg * C + r) * 256 + c1) = acc[r];
  }
  __syncthreads();
  // ---------- reduce1 + bias (+lab) + relu -> h ----------
  if (t < 128 * C) {
    const int r  = t >> 7;
    const int c0 = 2 * (t & 127);
    float2 s = *reinterpret_cast<const float2*>(B1 + c0);
    if (uselab) {
      const int j = u1h[done + r] & 1;
      const float2 lv = *reinterpret_cast<const float2*>(lab + j * 256 + c0);
      s.x += lv.x; s.y += lv.y;
    }
#pragma unroll
    for (int q = 0; q < 8; ++q) {
      const float2 p = *reinterpret_cast<const float2*>(red + (q * C + r) * 256 + c0);
      s.x += p.x; s.y += p.y;
    }
    s.x = fmaxf(s.x, 0.f); s.y = fmaxf(s.y, 0.f);
    *reinterpret_cast<float2*>(h + r * 256 + c0) = s;
  }
  __syncthreads();
  // ---------- layer 2 ----------
  {
    const int c2 = 2 * ln;
    const float* wb2 = W2 + 16 * wv * 128 + c2;
    float2 acc[C];
#pragma unroll
    for (int r = 0; r < C; ++r) acc[r] = make_float2(0.f, 0.f);
    float2 w0 = *reinterpret_cast<const float2*>(wb2);
    float2 w1 = *reinterpret_cast<const float2*>(wb2 + 128);
    float2 w2 = *reinterpret_cast<const float2*>(wb2 + 256);
    float2 w3 = *reinterpret_cast<const float2*>(wb2 + 384);
#pragma unroll 1
    for (int blk = 0; blk < 4; ++blk) {
      const float* wn = wb2 + 4 * ((blk < 3) ? blk + 1 : 3) * 128;
      const float2 n0 = *reinterpret_cast<const float2*>(wn);
      const float2 n1 = *reinterpret_cast<const float2*>(wn + 128);
      const float2 n2 = *reinterpret_cast<const float2*>(wn + 256);
      const float2 n3 = *reinterpret_cast<const float2*>(wn + 384);
#pragma unroll
      for (int r = 0; r < C; ++r) {
        const float4 hv = *reinterpret_cast<const float4*>(h + r * 256 + 16 * wv + 4 * blk);
        acc[r].x = fmaf(hv.x,w0.x, fmaf(hv.y,w1.x, fmaf(hv.z,w2.x, fmaf(hv.w,w3.x, acc[r].x))));
        acc[r].y = fmaf(hv.x,w0.y, fmaf(hv.y,w1.y, fmaf(hv.z,w2.y, fmaf(hv.w,w3.y, acc[r].y))));
      }
      w0 = n0; w1 = n1; w2 = n2; w3 = n3;
    }
#pragma unroll
    for (int r = 0; r < C; ++r)
      *reinterpret_cast<float2*>(red + (wv * C + r) * 128 + c2) = acc[r];
  }
  __syncthreads();
  // ---------- reduce2 + bias -> eout ----------
  if (t < 64 * C) {
    const int r  = t >> 6;
    const int c0 = 2 * (t & 63);
    float2 s = *reinterpret_cast<const float2*>(B2 + c0);
#pragma unroll
    for (int q = 0; q < 16; ++q) {
      const float2 p = *reinterpret_cast<const float2*>(red + (q * C + r) * 128 + c0);
      s.x += p.x; s.y += p.y;
    }
    *reinterpret_cast<float2*>(eout + r * 128 + c0) = s;
  }
  __syncthreads();
}

// ---- paired MLP chunk (levels 1..3 non-uniform): 16 rows as TWO independent
// C8 chunks across wave groups; identical weight addresses across groups ->
// group B hits L1; halves chunk count (R13-proven). R16's 2-pass despill
// REGRESSED +19% (serial-chain length beats spill traffic in this regime) —
// this is the R13/R15 single-pass version. ----
__device__ __forceinline__ void mlp_pair(
    const float* zl,
    const float* __restrict__ W1, const float* __restrict__ B1,
    const float* __restrict__ W2, const float* __restrict__ B2,
    const float* lab, bool uselab, const short* u1h, int done,
    float* red, float* h, float* eout)
{
  const int t  = threadIdx.x;
  const int wv = t >> 6;
  const int ln = t & 63;
  const int g  = wv >> 3;                        // wave group = chunk
  // ---------- layer 1: per group 4 kg x 2 halves ----------
  {
    const int kq = (wv >> 1) & 3;                // 64 k each
    const int c1 = (wv & 1) * 128 + 2 * ln;
    const float* wb = W1 + 64 * kq * 256 + c1;
    const float* zb = zl + g * 8 * 256 + 64 * kq;
    float2 acc[8];
#pragma unroll
    for (int r = 0; r < 8; ++r) acc[r] = make_float2(0.f, 0.f);
    float2 w0 = *reinterpret_cast<const float2*>(wb);
    float2 w1 = *reinterpret_cast<const float2*>(wb + 256);
    float2 w2 = *reinterpret_cast<const float2*>(wb + 512);
    float2 w3 = *reinterpret_cast<const float2*>(wb + 768);
#pragma unroll 1
    for (int blk = 0; blk < 16; ++blk) {         // 16 x 4 k
      const float* wn = wb + 4 * ((blk < 15) ? blk + 1 : 15) * 256;
      const float2 n0 = *reinterpret_cast<const float2*>(wn);
      const float2 n1 = *reinterpret_cast<const float2*>(wn + 256);
      const float2 n2 = *reinterpret_cast<const float2*>(wn + 512);
      const float2 n3 = *reinterpret_cast<const float2*>(wn + 768);
#pragma unroll
      for (int r = 0; r < 8; ++r) {
        const float4 z = *reinterpret_cast<const float4*>(zb + r * 256 + 4 * blk);
        acc[r].x = fmaf(z.x,w0.x, fmaf(z.y,w1.x, fmaf(z.z,w2.x, fmaf(z.w,w3.x, acc[r].x))));
        acc[r].y = fmaf(z.x,w0.y, fmaf(z.y,w1.y, fmaf(z.z,w2.y, fmaf(z.w,w3.y, acc[r].y))));
      }
      w0 = n0; w1 = n1; w2 = n2; w3 = n3;
    }
#pragma unroll
    for (int r = 0; r < 8; ++r)
      *reinterpret_cast<float2*>(red + ((g * 4 + kq) * 8 + r) * 256 + c1) = acc[r];
  }
  __syncthreads();
  // ---------- reduce1 + bias (+lab) + relu -> h (16 rows) ----------
  for (int idx = t; idx < 2048; idx += NTHR) {
    const int r16 = idx >> 7;
    const int c0  = 2 * (idx & 127);
    const int gg = r16 >> 3, rr = r16 & 7;
    float2 s = *reinterpret_cast<const float2*>(B1 + c0);
    if (uselab) {
      const int j = u1h[done + r16] & 1;
      const float2 lv = *reinterpret_cast<const float2*>(lab + j * 256 + c0);
      s.x += lv.x; s.y += lv.y;
    }
#pragma unroll
    for (int q = 0; q < 4; ++q) {
      const float2 p = *reinterpret_cast<const float2*>(red + ((gg * 4 + q) * 8 + rr) * 256 + c0);
      s.x += p.x; s.y += p.y;
    }
    s.x = fmaxf(s.x, 0.f); s.y = fmaxf(s.y, 0.f);
    *reinterpret_cast<float2*>(h + r16 * 256 + c0) = s;
  }
  __syncthreads();
  // ---------- layer 2: per group 8 kg x 32 k ----------
  {
    const int kq = wv & 7;
    const int c2 = 2 * ln;
    const float* wb2 = W2 + 32 * kq * 128 + c2;
    const float* hb = h + g * 8 * 256 + 32 * kq;
    float2 acc[8];
#pragma unroll
    for (int r = 0; r < 8; ++r) acc[r] = make_float2(0.f, 0.f);
    float2 w0 = *reinterpret_cast<const float2*>(wb2);
    float2 w1 = *reinterpret_cast<const float2*>(wb2 + 128);
    float2 w2 = *reinterpret_cast<const float2*>(wb2 + 256);
    float2 w3 = *reinterpret_cast<const float2*>(wb2 + 384);
#pragma unroll 1
    for (int blk = 0; blk < 8; ++blk) {          // 8 x 4 k
      const float* wn = wb2 + 4 * ((blk < 7) ? blk + 1 : 7) * 128;
      const float2 n0 = *reinterpret_cast<const float2*>(wn);
      const float2 n1 = *reinterpret_cast<const float2*>(wn + 128);
      const float2 n2 = *reinterpret_cast<const float2*>(wn + 256);
      const float2 n3 = *reinterpret_cast<const float2*>(wn + 384);
#pragma unroll
      for (int r = 0; r < 8; ++r) {
        const float4 hv = *reinterpret_cast<const float4*>(hb + r * 256 + 4 * blk);
        acc[r].x = fmaf(hv.x,w0.x, fmaf(hv.y,w1.x, fmaf(hv.z,w2.x, fmaf(hv.w,w3.x, acc[r].x))));
        acc[r].y = fmaf(hv.x,w0.y, fmaf(hv.y,w1.y, fmaf(hv.z,w2.y, fmaf(hv.w,w3.y, acc[r].y))));
      }
      w0 = n0; w1 = n1; w2 = n2; w3 = n3;
    }
#pragma unroll
    for (int r = 0; r < 8; ++r)
      *reinterpret_cast<float2*>(red + (wv * 8 + r) * 128 + c2) = acc[r];
  }
  __syncthreads();
  // ---------- reduce2 + bias -> eout (16 rows) ----------
  {
    const int r16 = t >> 6;
    const int c0  = 2 * (t & 63);
    const int gg = r16 >> 3, rr = r16 & 7;
    float2 s = *reinterpret_cast<const float2*>(B2 + c0);
#pragma unroll
    for (int q = 0; q < 8; ++q) {
      const float2 p = *reinterpret_cast<const float2*>(red + ((gg * 8 + q) * 8 + rr) * 128 + c0);
      s.x += p.x; s.y += p.y;
    }
    *reinterpret_cast<float2*>(eout + r16 * 128 + c0) = s;
  }
  __syncthreads();
}

// ---- fused check+speculative-bit chunk, l5 (R=4), contiguous z ----
template <int R>
__device__ __forceinline__ void fused_chunk(
    const float* zl,
    const float* __restrict__ Wc1_, const float* __restrict__ Bc1_,
    const float* __restrict__ Wc2_, const float* __restrict__ Bc2_,
    const float* __restrict__ Wb1_, const float* __restrict__ Bb1_,
    const float* __restrict__ Wb2_, const float* __restrict__ Bb2_,
    const float* lab,
    float* red, float* h, float* eout, float* spec)
{
  const int t  = threadIdx.x;
  const int wv = t >> 6;
  const int ln = t & 63;
  // ---------- layer 1: 8 kg x 2 col-halves; 2R partial rows ----------
  {
    const int kg = wv >> 1;
    const int c1 = (wv & 1) * 128 + 2 * ln;
    const float* wcb = Wc1_ + 32 * kg * 256 + c1;
    const float* wbb = Wb1_ + 32 * kg * 256 + c1;
    const float* zb  = zl + 32 * kg;
    float2 ac[R], ab[R];
#pragma unroll
    for (int r = 0; r < R; ++r) { ac[r] = make_float2(0.f,0.f); ab[r] = make_float2(0.f,0.f); }
    float2 c0 = *reinterpret_cast<const float2*>(wcb);
    float2 c1v = *reinterpret_cast<const float2*>(wcb + 256);
    float2 c2v = *reinterpret_cast<const float2*>(wcb + 512);
    float2 c3v = *reinterpret_cast<const float2*>(wcb + 768);
    float2 b0 = *reinterpret_cast<const float2*>(wbb);
    float2 b1 = *reinterpret_cast<const float2*>(wbb + 256);
    float2 b2 = *reinterpret_cast<const float2*>(wbb + 512);
    float2 b3 = *reinterpret_cast<const float2*>(wbb + 768);
#pragma unroll 1
    for (int blk = 0; blk < 8; ++blk) {
      const int nb = 4 * ((blk < 7) ? blk + 1 : 7);
      const float* wcn = wcb + nb * 256;
      const float* wbn = wbb + nb * 256;
      const float2 nc0 = *reinterpret_cast<const float2*>(wcn);
      const float2 nc1 = *reinterpret_cast<const float2*>(wcn + 256);
      const float2 nc2 = *reinterpret_cast<const float2*>(wcn + 512);
      const float2 nc3 = *reinterpret_cast<const float2*>(wcn + 768);
      const float2 nb0 = *reinterpret_cast<const float2*>(wbn);
      const float2 nb1 = *reinterpret_cast<const float2*>(wbn + 256);
      const float2 nb2 = *reinterpret_cast<const float2*>(wbn + 512);
      const float2 nb3 = *reinterpret_cast<const float2*>(wbn + 768);
#pragma unroll
      for (int r = 0; r < R; ++r) {
        const float4 z = *reinterpret_cast<const float4*>(zb + r * 256 + 4 * blk);
        ac[r].x = fmaf(z.x,c0.x, fmaf(z.y,c1v.x, fmaf(z.z,c2v.x, fmaf(z.w,c3v.x, ac[r].x))));
        ac[r].y = fmaf(z.x,c0.y, fmaf(z.y,c1v.y, fmaf(z.z,c2v.y, fmaf(z.w,c3v.y, ac[r].y))));
        ab[r].x = fmaf(z.x,b0.x, fmaf(z.y,b1.x, fmaf(z.z,b2.x, fmaf(z.w,b3.x, ab[r].x))));
        ab[r].y = fmaf(z.x,b0.y, fmaf(z.y,b1.y, fmaf(z.z,b2.y, fmaf(z.w,b3.y, ab[r].y))));
      }
      c0 = nc0; c1v = nc1; c2v = nc2; c3v = nc3;
      b0 = nb0; b1 = nb1; b2 = nb2; b3 = nb3;
    }
#pragma unroll
    for (int r = 0; r < R; ++r) {
      *reinterpret_cast<float2*>(red + (kg * 2 * R + r) * 256 + c1) = ac[r];
      *reinterpret_cast<float2*>(red + (kg * 2 * R + R + r) * 256 + c1) = ab[r];
    }
  }
  __syncthreads();
  // ---------- reduce1 -> h: 3R rows ----------
  for (int idx = t; idx < 3 * R * 128; idx += NTHR) {
    const int r  = idx >> 7;
    const int c0 = 2 * (idx & 127);
    const int pr = (r < 2 * R) ? r : r - R;
    float2 s;
    if (r < R) {
      s = *reinterpret_cast<const float2*>(Bc1_ + c0);
    } else {
      s = *reinterpret_cast<const float2*>(Bb1_ + c0);
      const float2 lv = *reinterpret_cast<const float2*>(lab + ((r < 2 * R) ? 0 : 256) + c0);
      s.x += lv.x; s.y += lv.y;
    }
#pragma unroll
    for (int q = 0; q < 8; ++q) {
      const float2 p = *reinterpret_cast<const float2*>(red + (q * 2 * R + pr) * 256 + c0);
      s.x += p.x; s.y += p.y;
    }
    s.x = fmaxf(s.x, 0.f); s.y = fmaxf(s.y, 0.f);
    *reinterpret_cast<float2*>(h + r * 256 + c0) = s;
  }
  __syncthreads();
  // ---------- layer 2: 8 kg x 2 col-halves (1 col/lane); 3R rows ----------
  {
    const int kg = wv >> 1;
    const int c2 = (wv & 1) * 64 + ln;
    const float* wcb = Wc2_ + 32 * kg * 128 + c2;
    const float* wbb = Wb2_ + 32 * kg * 128 + c2;
    float acc[3 * R];
#pragma unroll
    for (int r = 0; r < 3 * R; ++r) acc[r] = 0.f;
    float c0v = wcb[0], c1v = wcb[128], c2v = wcb[256], c3v = wcb[384];
    float b0v = wbb[0], b1v = wbb[128], b2v = wbb[256], b3v = wbb[384];
#pragma unroll 1
    for (int blk = 0; blk < 8; ++blk) {
      const int nb = 4 * ((blk < 7) ? blk + 1 : 7);
      const float* wcn = wcb + nb * 128;
      const float* wbn = wbb + nb * 128;
      const float nc0 = wcn[0], nc1 = wcn[128], nc2 = wcn[256], nc3 = wcn[384];
      const float nb0 = wbn[0], nb1 = wbn[128], nb2 = wbn[256], nb3 = wbn[384];
      const float* hb = h + 32 * kg + 4 * blk;
#pragma unroll
      for (int r = 0; r < 3 * R; ++r) {
        const float4 hv = *reinterpret_cast<const float4*>(hb + r * 256);
        if (r < R)
          acc[r] = fmaf(hv.x,c0v, fmaf(hv.y,c1v, fmaf(hv.z,c2v, fmaf(hv.w,c3v, acc[r]))));
        else
          acc[r] = fmaf(hv.x,b0v, fmaf(hv.y,b1v, fmaf(hv.z,b2v, fmaf(hv.w,b3v, acc[r]))));
      }
      c0v = nc0; c1v = nc1; c2v = nc2; c3v = nc3;
      b0v = nb0; b1v = nb1; b2v = nb2; b3v = nb3;
    }
#pragma unroll
    for (int r = 0; r < 3 * R; ++r)
      red[(kg * 3 * R + r) * 128 + c2] = acc[r];
  }
  __syncthreads();
  // ---------- reduce2: check -> eout, bit -> spec[2][R][128] ----------
  for (int idx = t; idx < 3 * R * 128; idx += NTHR) {
    const int r = idx >> 7;
    const int c = idx & 127;
    float s = (r < R) ? Bc2_[c] : Bb2_[c];
#pragma unroll
    for (int q = 0; q < 8; ++q) s += red[(q * 3 * R + r) * 128 + c];
    if (r < R)            eout[r * 128 + c] = s;
    else if (r < 2 * R)   spec[(r - R) * 128 + c] = s;
    else                  spec[R * 128 + (r - 2 * R) * 128 + c] = s;
  }
  __syncthreads();
}

__global__ void sc_setup(const int* __restrict__ info_set,
                         const float* __restrict__ E_obs,
                         const float* __restrict__ E_lab,
                         const float* __restrict__ Wb1,
                         const float* __restrict__ Wc2, const float* __restrict__ bc2,
                         const float* __restrict__ Wb2, const float* __restrict__ bb2,
                         const float* __restrict__ Wl, const float* __restrict__ bl,
                         int* __restrict__ pos2k, float* __restrict__ lab1,
                         float* __restrict__ eroot, float* __restrict__ cvb)
{
  const int t = threadIdx.x;   // 256 threads
  pos2k[t] = -1;
  __syncthreads();
  if (t < 128) pos2k[info_set[t]] = t;
  eroot[t] = E_obs[2 * 128 + (t & 127)];
  for (int j = 0; j < 2; ++j) {
    float s = 0.0f;
    for (int k = 0; k < 128; ++k)
      s = fmaf(E_lab[j * 128 + k], Wb1[(256 + k) * 256 + t], s);
    lab1[j * 256 + t] = s;
  }
  {
    float sc = 0.f, sb = 0.f;
    for (int c = 0; c < 128; ++c) {
      sc = fmaf(Wc2[t * 128 + c], Wl[c], sc);
      sb = fmaf(Wb2[t * 128 + c], Wl[c], sb);
    }
    cvb[t] = sc;
    cvb[256 + t] = sb;
  }
  if (t == 0) {
    float s = bl[0];
    for (int c = 0; c < 128; ++c) s = fmaf(bc2[c], Wl[c], s);
    cvb[512] = s;
  }
  if (t == 1) {
    float s = bl[0];
    for (int c = 0; c < 128; ++c) s = fmaf(bb2[c], Wl[c], s);
    cvb[513] = s;
  }
}

__global__ __launch_bounds__(NTHR)
__attribute__((amdgpu_waves_per_eu(4, 4)))
void sc_main(const int* __restrict__ info_bits, const float* __restrict__ rin,
             const float* __restrict__ Wc1, const float* __restrict__ bc1,
             const float* __restrict__ Wc2, const float* __restrict__ bc2,
             const float* __restrict__ Wb1, const float* __restrict__ bb1,
             const float* __restrict__ Wb2, const float* __restrict__ bb2,
             const int* __restrict__ pos2k, const float* __restrict__ lab1_g,
             const float* __restrict__ eroot_g, const float* __restrict__ cvb_g,
             float* __restrict__ wsall, float* __restrict__ out)
{
  const int b = blockIdx.x;
  const int t = threadIdx.x;
  float* e1g = wsall + (size_t)b * EG_STRIDE;      // level-1 e (global)

  __shared__ __align__(16) float red[16384];       // 64 KB; tail [12288,16384) =
                                                   //   l6 right-variant half-sums
  __shared__ __align__(16) float h_lds[4096];      // 16 KB hidden (16 rows) / z-stage
  __shared__ __align__(16) float scratch[1536];    //  6 KB: lvl-0 out UNION specs
  __shared__ __align__(16) float e2[8192];         // 32 KB level-2 e
  __shared__ __align__(16) float e3[4096];         // 16 KB level-3 e
  __shared__ __align__(16) float e4[2048];         //  8 KB level-4 e
  __shared__ __align__(16) float e567[1792];       // levels 5..7: 8,4,2 rows
  __shared__ __align__(16) float lab_lds[512];
  __shared__ __align__(16) float eroot[256];
  __shared__ __align__(16) float cvb_lds[516];     // cv|bv|cc|cb
  __shared__ __align__(16) float bias_lds[512];    // bc1|bb1
  __shared__ float rrow[256];
  __shared__ short xh[520];
  __shared__ short ibits[128];
  __shared__ short p2k_l[256];

  float* xO = out;
  float* fO = out + 32768;
  float* uO = out + 65536;
  float* pO = out + 98304;
  float* rO = out + 131072;

  // ---- prologue ----
  if (t < 512) lab_lds[t] = lab1_g[t];
  if (t < 514) cvb_lds[t] = cvb_g[t];
  if (t < 256) bias_lds[t] = bc1[t];
  else if (t < 512) bias_lds[256 + (t - 256)] = bb1[t - 256];
  if (t < 256) {
    eroot[t]  = eroot_g[t];
    p2k_l[t]  = (short)pos2k[t];
    const float rv = rin[b * 256 + t];
    rrow[t]   = rv;
    rO[b * 256 + t] = rv;
    fO[b * 256 + t] = (pos2k[t] >= 0) ? 2.0f : 1.0f;
  }
  if (t < 128) ibits[t] = (short)info_bits[b * 128 + t];
  if (t == 0) { xh[512] = 0; xh[513] = 1; }        // constant u1h for lvl-0 bit
  __syncthreads();

  // ---- uniform-first-descent flag (R15-proven): e1g must STILL be written
  // by l0-check — the l1-bit visit at i=62 stages left-e1 from e1g. ----
  bool fdesc = true;

  // ---- levels 1..4 ----
  auto run_level = [&](int l, bool isbit) {
    const float* W1 = isbit ? Wb1 : Wc1;
    const float* B1 = isbit ? bb1 : bc1;
    const float* W2 = isbit ? Wb2 : Wc2;
    const float* B2 = isbit ? bb2 : bc2;
    const short* u1h = xh + xoff(l);
    if (!isbit && fdesc) {            // uniform descent: C1 + broadcast
      const float* zu; float* eo; int bsz;
      switch (l) {
        case 1:  zu = scratch; eo = e2;   bsz = 8192; break;
        case 2:  zu = e2;      eo = e3;   bsz = 4096; break;
        case 3:  zu = e3;      eo = e4;   bsz = 2048; break;
        default: zu = e4;      eo = e567; bsz = 1024; break;   // l == 4
      }
      mlp_chunk<1>(zu, 0, W1, B1, W2, B2, lab_lds, false, u1h, 0,
                   red, h_lds, eo);
      for (int idx = t + 128; idx < bsz; idx += NTHR) eo[idx] = eo[idx & 127];
      __syncthreads();
      return;
    }
    if (l == 4) {
      mlp_chunk<8>(e4, 256, W1, B1, W2, B2, lab_lds, isbit, u1h, 0,
                   red, h_lds, e567);
      return;
    }
    const int rows = 128 >> l;
    const float* ein; float* eo;
    switch (l) {
      case 1:  ein = nullptr; eo = e2; break;
      case 2:  ein = e2;      eo = e3; break;
      default: ein = e3;      eo = e4; break;      // l == 3
    }
    for (int done = 0; done < rows; done += 16) {
      const float* zl;
      if (l == 1) {   // stage 16 rows into h_lds (dead until reduce1 rewrites)
        const float4* src = reinterpret_cast<const float4*>(e1g + done * 256);
        for (int i4 = t; i4 < 1024; i4 += NTHR)
          reinterpret_cast<float4*>(h_lds)[i4] = src[i4];
        __syncthreads();
        zl = h_lds;
      } else {
        zl = ein + done * 256;
      }
      mlp_pair(zl, W1, B1, W2, B2, lab_lds, isbit, u1h, done,
               red, h_lds, eo + done * 128);
    }
  };

  // ---- level 0 special: check = C1; output duplicated in scratch[0:256)
  // for the uniform l1 read AND broadcast to e1g (R14 lesson: the l1-bit
  // visit at i=62 precedes l0-bit and stages from e1g). ----
  auto run_level0 = [&](bool isbit) {
    if (!isbit) {
      mlp_chunk<1>(eroot, 0, Wc1, bc1, Wc2, bc2, lab_lds, false, xh, 0, red, h_lds, scratch);
      if (t < 128) scratch[128 + t] = scratch[t];
      for (int i4 = t; i4 < 4096; i4 += NTHR)
        reinterpret_cast<float4*>(e1g)[i4] =
            reinterpret_cast<const float4*>(scratch)[i4 & 31];
      __syncthreads();
    } else {
      mlp_chunk<2>(eroot, 0, Wb1, bb1, Wb2, bb2, lab_lds, true, xh + 512, 0, red, h_lds, scratch);
      for (int i4 = t; i4 < 4096; i4 += NTHR)
        reinterpret_cast<float4*>(e1g)[i4] =
            reinterpret_cast<const float4*>(scratch)[(xh[i4 >> 5] & 1) * 32 + (i4 & 31)];
      __syncthreads();
    }
  };

  // ---- shared l6 tail: layer2 (6 h rows) + reduce2 -> e7 + spec6 ----
  auto l6_tail = [&]() {
    const int wv = t >> 6;
    const int ln = t & 63;
    {
      const int kg = wv >> 1;
      const int c2 = (wv & 1) * 64 + ln;
      const float* wcb = Wc2 + 32 * kg * 128 + c2;
      const float* wbb = Wb2 + 32 * kg * 128 + c2;
      float acc[6];
#pragma unroll
      for (int r = 0; r < 6; ++r) acc[r] = 0.f;
      float c0v = wcb[0], c1v = wcb[128], c2v = wcb[256], c3v = wcb[384];
      float b0v = wbb[0], b1v = wbb[128], b2v = wbb[256], b3v = wbb[384];
#pragma unroll 1
      for (int blk = 0; blk < 8; ++blk) {
        const int nb = 4 * ((blk < 7) ? blk + 1 : 7);
        const float* wcn = wcb + nb * 128;
        const float* wbn = wbb + nb * 128;
        const float nc0 = wcn[0], nc1 = wcn[128], nc2 = wcn[256], nc3 = wcn[384];
        const float nb0 = wbn[0], nb1 = wbn[128], nb2 = wbn[256], nb3 = wbn[384];
        const float* hb = h_lds + 32 * kg + 4 * blk;
#pragma unroll
        for (int r = 0; r < 6; ++r) {
          const float4 hv = *reinterpret_cast<const float4*>(hb + r * 256);
          if (r < 2)
            acc[r] = fmaf(hv.x,c0v, fmaf(hv.y,c1v, fmaf(hv.z,c2v, fmaf(hv.w,c3v, acc[r]))));
          else
            acc[r] = fmaf(hv.x,b0v, fmaf(hv.y,b1v, fmaf(hv.z,b2v, fmaf(hv.w,b3v, acc[r]))));
        }
        c0v = nc0; c1v = nc1; c2v = nc2; c3v = nc3;
        b0v = nb0; b1v = nb1; b2v = nb2; b3v = nb3;
      }
#pragma unroll
      for (int r = 0; r < 6; ++r)
        red[(kg * 6 + r) * 128 + c2] = acc[r];
    }
    __syncthreads();
    if (t < 768) {
      const int r = t >> 7;
      const int c = t & 127;
      float s = (r < 2) ? bc2[c] : bb2[c];
#pragma unroll
      for (int q = 0; q < 8; ++q) s += red[(q * 6 + r) * 128 + c];
      float* e7 = e567 + 1536;
      float* spec6 = scratch + 1024;
      if (r < 2)        e7[r * 128 + c] = s;
      else if (r < 4)   spec6[(r - 2) * 128 + c] = s;
      else              spec6[256 + (r - 4) * 128 + c] = s;
    }
    __syncthreads();
  };

  // ---- f6-LEFT (R12-proven): one Wc1+Wb1 stream serves this exec AND the
  // later f6-RIGHT via red-tail half-sums. ----
  auto run_f6_left = [&]() {
    const int wv = t >> 6;
    const int ln = t & 63;
    {
      const int kg  = wv >> 2;
      const int col = (wv & 3) * 64 + ln;
      const float* wcb = Wc1 + 64 * kg * 256 + col;
      const float* wbb = Wb1 + 64 * kg * 256 + col;
      const float* zL  = e567 + 1024 + 64 * kg;
      const int rrofs = (kg >> 1) * 128 + (kg & 1) * 64;
      float aLc0 = 0.f, aLc1 = 0.f, aLb0 = 0.f, aLb1 = 0.f;
      float aRc[4], aRb[4];
#pragma unroll
      for (int q = 0; q < 4; ++q) { aRc[q] = 0.f; aRb[q] = 0.f; }
      float wc0 = wcb[0], wc1 = wcb[256], wc2 = wcb[512], wc3 = wcb[768];
      float wb0 = wbb[0], wb1 = wbb[256], wb2 = wbb[512], wb3 = wbb[768];
#pragma unroll 1
      for (int blk = 0; blk < 16; ++blk) {
        const float* wcn = wcb + 4 * ((blk < 15) ? blk + 1 : 15) * 256;
        const float* wbn = wbb + 4 * ((blk < 15) ? blk + 1 : 15) * 256;
        const float nc0 = wcn[0], nc1 = wcn[256], nc2 = wcn[512], nc3 = wcn[768];
        const float nb0 = wbn[0], nb1 = wbn[256], nb2 = wbn[512], nb3 = wbn[768];
        {
          const float4 z = *reinterpret_cast<const float4*>(zL + 4 * blk);
          aLc0 = fmaf(z.x,wc0, fmaf(z.y,wc1, fmaf(z.z,wc2, fmaf(z.w,wc3, aLc0))));
          aLb0 = fmaf(z.x,wb0, fmaf(z.y,wb1, fmaf(z.z,wb2, fmaf(z.w,wb3, aLb0))));
        }
        {
          const float4 z = *reinterpret_cast<const float4*>(zL + 256 + 4 * blk);
          aLc1 = fmaf(z.x,wc0, fmaf(z.y,wc1, fmaf(z.z,wc2, fmaf(z.w,wc3, aLc1))));
          aLb1 = fmaf(z.x,wb0, fmaf(z.y,wb1, fmaf(z.z,wb2, fmaf(z.w,wb3, aLb1))));
        }
#pragma unroll
        for (int r = 0; r < 2; ++r) {
#pragma unroll
          for (int v = 0; v < 2; ++v) {
            const float4 z = *reinterpret_cast<const float4*>(
                scratch + v * 512 + 2 * r * 128 + rrofs + 4 * blk);
            aRc[r * 2 + v] = fmaf(z.x,wc0, fmaf(z.y,wc1, fmaf(z.z,wc2, fmaf(z.w,wc3, aRc[r * 2 + v]))));
            aRb[r * 2 + v] = fmaf(z.x,wb0, fmaf(z.y,wb1, fmaf(z.z,wb2, fmaf(z.w,wb3, aRb[r * 2 + v]))));
          }
        }
        wc0 = nc0; wc1 = nc1; wc2 = nc2; wc3 = nc3;
        wb0 = nb0; wb1 = nb1; wb2 = nb2; wb3 = nb3;
      }
      red[(kg * 12 + 0) * 256 + col] = aLc0;
      red[(kg * 12 + 1) * 256 + col] = aLc1;
      red[(kg * 12 + 2) * 256 + col] = aLb0;
      red[(kg * 12 + 3) * 256 + col] = aLb1;
#pragma unroll
      for (int q = 0; q < 4; ++q) {
        red[(kg * 12 + 4 + q) * 256 + col] = aRc[q];
        red[(kg * 12 + 8 + q) * 256 + col] = aRb[q];
      }
    }
    __syncthreads();
    for (int idx = t; idx < 1536; idx += NTHR) {
      const int r6  = idx >> 8;
      const int col = idx & 255;
      const int pr  = (r6 < 2) ? r6 : 2 + ((r6 - 2) & 1);
      float s = (r6 < 2) ? bias_lds[col] : bias_lds[256 + col];
      if (r6 >= 2) s += lab_lds[((r6 >= 4) ? 256 : 0) + col];
#pragma unroll
      for (int q = 0; q < 4; ++q) s += red[(q * 12 + pr) * 256 + col];
      h_lds[r6 * 256 + col] = fmaxf(s, 0.f);
    }
    for (int idx = t; idx < 4096; idx += NTHR) {
      const int col  = idx & 255;
      const int q    = idx >> 8;
      const int v    = q & 1;
      const int half = (q >> 1) & 1;
      const int r    = (q >> 2) & 1;
      const int type = q >> 3;
      const int rowi = (type ? 8 : 4) + r * 2 + v;
      red[12288 + q * 256 + col] =
          red[((half * 2 + 0) * 12 + rowi) * 256 + col] +
          red[((half * 2 + 1) * 12 + rowi) * 256 + col];
    }
    __syncthreads();
    l6_tail();
  };

  auto run_f6_right = [&]() {
    for (int idx = t; idx < 1536; idx += NTHR) {
      const int r6  = idx >> 8;
      const int col = idx & 255;
      const int type = (r6 < 2) ? 0 : 1;
      const int r    = (r6 < 2) ? r6 : ((r6 - 2) & 1);
      const int v0 = xh[xoff(5) + 2 * r] & 1;
      const int v1 = xh[xoff(5) + 2 * r + 1] & 1;
      const int q0 = ((type * 2 + r) * 2 + 0) * 2 + v0;
      const int q1 = ((type * 2 + r) * 2 + 1) * 2 + v1;
      float s = red[12288 + q0 * 256 + col] + red[12288 + q1 * 256 + col];
      s += (type == 0) ? bias_lds[col] : bias_lds[256 + col];
      if (type) s += lab_lds[((r6 >= 4) ? 256 : 0) + col];
      h_lds[r6 * 256 + col] = fmaxf(s, 0.f);
    }
    __syncthreads();
    l6_tail();
  };

  // ---- shared leaf-decide (lane 0 of wave 0 only) ----
  auto decide_pair = [&](float d0, float d1, float d2, int i, int side) {
    int xv0, xv1;
    {
      const float p  = 1.0f / (1.0f + expf(-d0));
      const float rv = rrow[i];
      const int  hd     = (rv > p) ? 1 : 0;
      const bool frozen = fabsf(p - 0.5f) > 0.25f;
      const int  k  = p2k_l[i];
      const int  fc = (k >= 0) ? (int)ibits[k] : 2;
      xv0 = (fc == 2 || frozen) ? hd : fc;
      pO[b * 256 + i] = p;
      uO[b * 256 + i] = (float)xv0;
    }
    {
      const float dv = (xv0 & 1) ? d2 : d1;
      const float p  = 1.0f / (1.0f + expf(-dv));
      const float rv = rrow[i + 1];
      const int  hd     = (rv > p) ? 1 : 0;
      const bool frozen = fabsf(p - 0.5f) > 0.25f;
      const int  k  = p2k_l[i + 1];
      const int  fc = (k >= 0) ? (int)ibits[k] : 2;
      xv1 = (fc == 2 || frozen) ? hd : fc;
      pO[b * 256 + i + 1] = p;
      uO[b * 256 + i + 1] = (float)xv1;
    }
    const int base = xoff(6) + side * 2;
    xh[base]     = (short)(xv0 ^ xv1);
    xh[base + 1] = (short)xv1;
  };

  // ---- l7 LEFT: one weight stream serves both l7 pairs (R11-proven) ----
  auto run_l7_left = [&](const float* zh0, const float* zh1, int i) {
    const int wv = t >> 6;
    const int ln = t & 63;
    {
      const int kg = wv >> 1;
      const int c1 = (wv & 1) * 128 + 2 * ln;
      const float* wcb = Wc1 + 32 * kg * 256 + c1;
      const float* wbb = Wb1 + 32 * kg * 256 + c1;
      const float* zp = (kg >= 4) ? zh1 : zh0;
      const float* vA = scratch + 1024 + ((kg >= 4) ? 128 : 0);
      const int kb = 32 * (kg & 3);
      float2 acL = make_float2(0.f,0.f), abL = make_float2(0.f,0.f);
      float2 ac0 = make_float2(0.f,0.f), ab0 = make_float2(0.f,0.f);
      float2 ac1 = make_float2(0.f,0.f), ab1 = make_float2(0.f,0.f);
#pragma unroll 1
      for (int blk = 0; blk < 8; ++blk) {
        const float* wcp = wcb + 4 * blk * 256;
        const float* wbp = wbb + 4 * blk * 256;
        const float2 c0 = *reinterpret_cast<const float2*>(wcp);
        const float2 c1v = *reinterpret_cast<const float2*>(wcp + 256);
        const float2 c2v = *reinterpret_cast<const float2*>(wcp + 512);
        const float2 c3v = *reinterpret_cast<const float2*>(wcp + 768);
        const float2 b0 = *reinterpret_cast<const float2*>(wbp);
        const float2 b1 = *reinterpret_cast<const float2*>(wbp + 256);
        const float2 b2 = *reinterpret_cast<const float2*>(wbp + 512);
        const float2 b3 = *reinterpret_cast<const float2*>(wbp + 768);
        const float4 zL = *reinterpret_cast<const float4*>(zp + kb + 4 * blk);
        acL.x = fmaf(zL.x,c0.x, fmaf(zL.y,c1v.x, fmaf(zL.z,c2v.x, fmaf(zL.w,c3v.x, acL.x))));
        acL.y = fmaf(zL.x,c0.y, fmaf(zL.y,c1v.y, fmaf(zL.z,c2v.y, fmaf(zL.w,c3v.y, acL.y))));
        abL.x = fmaf(zL.x,b0.x, fmaf(zL.y,b1.x, fmaf(zL.z,b2.x, fmaf(zL.w,b3.x, abL.x))));
        abL.y = fmaf(zL.x,b0.y, fmaf(zL.y,b1.y, fmaf(zL.z,b2.y, fmaf(zL.w,b3.y, abL.y))));
        const float4 z0 = *reinterpret_cast<const float4*>(vA + kb + 4 * blk);
        ac0.x = fmaf(z0.x,c0.x, fmaf(z0.y,c1v.x, fmaf(z0.z,c2v.x, fmaf(z0.w,c3v.x, ac0.x))));
        ac0.y = fmaf(z0.x,c0.y, fmaf(z0.y,c1v.y, fmaf(z0.z,c2v.y, fmaf(z0.w,c3v.y, ac0.y))));
        ab0.x = fmaf(z0.x,b0.x, fmaf(z0.y,b1.x, fmaf(z0.z,b2.x, fmaf(z0.w,b3.x, ab0.x))));
        ab0.y = fmaf(z0.x,b0.y, fmaf(z0.y,b1.y, fmaf(z0.z,b2.y, fmaf(z0.w,b3.y, ab0.y))));
        const float4 z1 = *reinterpret_cast<const float4*>(vA + 256 + kb + 4 * blk);
        ac1.x = fmaf(z1.x,c0.x, fmaf(z1.y,c1v.x, fmaf(z1.z,c2v.x, fmaf(z1.w,c3v.x, ac1.x))));
        ac1.y = fmaf(z1.x,c0.y, fmaf(z1.y,c1v.y, fmaf(z1.z,c2v.y, fmaf(z1.w,c3v.y, ac1.y))));
        ab1.x = fmaf(z1.x,b0.x, fmaf(z1.y,b1.x, fmaf(z1.z,b2.x, fmaf(z1.w,b3.x, ab1.x))));
        ab1.y = fmaf(z1.x,b0.y, fmaf(z1.y,b1.y, fmaf(z1.z,b2.y, fmaf(z1.w,b3.y, ab1.y))));
      }
      *reinterpret_cast<float2*>(red + (kg * 6 + 0) * 256 + c1) = acL;
      *reinterpret_cast<float2*>(red + (kg * 6 + 1) * 256 + c1) = abL;
      *reinterpret_cast<float2*>(red + (kg * 6 + 2) * 256 + c1) = ac0;
      *reinterpret_cast<float2*>(red + (kg * 6 + 3) * 256 + c1) = ab0;
      *reinterpret_cast<float2*>(red + (kg * 6 + 4) * 256 + c1) = ac1;
      *reinterpret_cast<float2*>(red + (kg * 6 + 5) * 256 + c1) = ab1;
    }
    __syncthreads();
    if (t < 64) {
      float p0 = 0.f, p1 = 0.f, p2 = 0.f;
#pragma unroll
      for (int ii = 0; ii < 4; ++ii) {
        const int c = t + 64 * ii;
        float r0 = 0.f, r1 = 0.f;
#pragma unroll
        for (int q = 0; q < 8; ++q) {
          r0 += red[(q * 6 + 0) * 256 + c];
          r1 += red[(q * 6 + 1) * 256 + c];
        }
        const float s0 = fmaxf(bias_lds[c] + r0, 0.f);
        const float s1 = fmaxf(bias_lds[256 + c] + lab_lds[c] + r1, 0.f);
        const float s2 = fmaxf(bias_lds[256 + c] + lab_lds[256 + c] + r1, 0.f);
        const float vc = cvb_lds[c], vb = cvb_lds[256 + c];
        p0 = fmaf(s0, vc, p0); p1 = fmaf(s1, vb, p1); p2 = fmaf(s2, vb, p2);
      }
#pragma unroll
      for (int m = 32; m >= 1; m >>= 1) {
        p0 += __shfl_xor(p0, m); p1 += __shfl_xor(p1, m); p2 += __shfl_xor(p2, m);
      }
      if (t == 0)
        decide_pair(p0 + cvb_lds[512], p1 + cvb_lds[513], p2 + cvb_lds[513], i, 0);
    }
    __syncthreads();
  };

  auto run_l7_right = [&](int i, int side) {
    if (t < 64) {
      const int bit0 = xh[xoff(6) + 0] & 1;
      const int bit1 = xh[xoff(6) + 1] & 1;
      float p0 = 0.f, p1 = 0.f, p2 = 0.f;
#pragma unroll
      for (int ii = 0; ii < 4; ++ii) {
        const int c = t + 64 * ii;
        float r0 = 0.f, r1 = 0.f;
#pragma unroll
        for (int q = 0; q < 8; ++q) {
          const int vo = ((q < 4) ? bit0 : bit1) * 2;
          r0 += red[(q * 6 + 2 + vo) * 256 + c];
          r1 += red[(q * 6 + 3 + vo) * 256 + c];
        }
        const float s0 = fmaxf(bias_lds[c] + r0, 0.f);
        const float s1 = fmaxf(bias_lds[256 + c] + lab_lds[c] + r1, 0.f);
        const float s2 = fmaxf(bias_lds[256 + c] + lab_lds[256 + c] + r1, 0.f);
        const float vc = cvb_lds[c], vb = cvb_lds[256 + c];
        p0 = fmaf(s0, vc, p0); p1 = fmaf(s1, vb, p1); p2 = fmaf(s2, vb, p2);
      }
#pragma unroll
      for (int m = 32; m >= 1; m >>= 1) {
        p0 += __shfl_xor(p0, m); p1 += __shfl_xor(p1, m); p2 += __shfl_xor(p2, m);
      }
      if (t == 0)
        decide_pair(p0 + cvb_lds[512], p1 + cvb_lds[513], p2 + cvb_lds[513], i, side);
    }
    __syncthreads();
  };

  auto do_combine = [&](int l, int side) {
    const int n = 256 >> l, half = n >> 1;
    if (t < half) {
      const int u1 = xh[xoff(l) + t];
      const int u2 = xh[xoff(l) + half + t];
      if (l > 0) {
        const int base = xoff(l - 1) + side * n;
        xh[base + 2 * t]     = (short)(u1 ^ u2);
        xh[base + 2 * t + 1] = (short)u2;
      } else {
        xO[b * 256 + 2 * t]     = (float)(u1 ^ u2);
        xO[b * 256 + 2 * t + 1] = (float)u2;
      }
    }
    __syncthreads();
  };

  // ---- SC traversal ----
  const float* l7z0 = nullptr; const float* l7z1 = nullptr;
  bool l6left = true;
  int i = 0, l = 0;
  bool isbit = false;
  while (true) {
    if (l == 7) {
      fdesc = false;
      const int s2 = __builtin_ctz(i + 2);
      if ((i & 2) == 0) run_l7_left(l7z0, l7z1, i);
      else              run_l7_right(i, (1 < s2) ? 1 : 0);
      if (i == 254) {
        for (int j = 2; j <= 8; ++j) do_combine(8 - j, (j < 8) ? 1 : 0);
        break;
      }
      i += 2;
      for (int j = 2; j <= s2; ++j) do_combine(8 - j, (j < s2) ? 1 : 0);
      l = 7 - s2;
      isbit = true;
      continue;
    }
    if (l >= 5) {
      if (isbit) {
        if (l == 5) l6left = false;   // next f6 selects via xh bits (no stream)
      } else {
        if (l == 5) {
          fused_chunk<4>(e567, Wc1, bc1, Wc2, bc2, Wb1, bb1, Wb2, bb2, lab_lds,
                         red, h_lds, e567 + 1024, scratch);
          l6left = true;
        } else {          // l == 6
          if (l6left) run_f6_left();
          else        run_f6_right();
          l7z0 = e567 + 1536; l7z1 = e567 + 1536 + 128;
        }
      }
    } else if (l == 0) {
      run_level0(isbit);
    } else {
      run_level(l, isbit);
    }
    ++l; isbit = false;
  }
}

extern "C" void kernel_launch(void* const* d_in, const int* in_sizes, int n_in,
                              void* d_out, int out_size, void* d_ws, size_t ws_size,
                              hipStream_t stream)
{
  const int*   info_bits = (const int*)  d_in[0];
  const float* rin       = (const float*)d_in[1];
  const int*   info_set  = (const int*)  d_in[2];
  const float* E_obs     = (const float*)d_in[3];
  const float* E_lab     = (const float*)d_in[4];
  const float* Wc1 = (const float*)d_in[5];
  const float* bc1 = (const float*)d_in[6];
  const float* Wc2 = (const float*)d_in[7];
  const float* bc2 = (const float*)d_in[8];
  const float* Wb1 = (const float*)d_in[9];
  const float* bb1 = (const float*)d_in[10];
  const float* Wb2 = (const float*)d_in[11];
  const float* bb2 = (const float*)d_in[12];
  const float* Wl  = (const float*)d_in[13];
  const float* bl  = (const float*)d_in[14];

  int*   pos2k = (int*)d_ws;                 // [0,256) ints
  float* lab1  = (float*)d_ws + 256;         // [256,768)
  float* eroot = (float*)d_ws + 768;         // [768,1024)
  float* cvb   = (float*)d_ws + 1024;        // [1024,1538): cv|bv|cc|cb
  float* wsall = (float*)d_ws + 2048;        // 128 x EG_STRIDE floats

  hipLaunchKernelGGL(sc_setup, dim3(1), dim3(256), 0, stream,
                     info_set, E_obs, E_lab, Wb1, Wc2, bc2, Wb2, bb2,
                     Wl, bl, pos2k, lab1, eroot, cvb);
  hipLaunchKernelGGL(sc_main, dim3(128), dim3(NTHR), 0, stream,
                     info_bits, rin,
                     Wc1, bc1, Wc2, bc2, Wb1, bb1, Wb2, bb2,
                     pos2k, lab1, eroot, cvb, wsall, (float*)d_out);
}